// Round 3
// baseline (989.279 us; speedup 1.0000x reference)
//
#include <hip/hip_runtime.h>

#define NN_TOT 208896      // 32*96*68 nodes
#define E_TOT  1671168     // NN_TOT*8 edges
#define B_SZ   32
#define T_SZ   96
#define NPF    68          // nodes per frame
#define HID    128

// ---------------- degree count ----------------
__global__ __launch_bounds__(256) void k_deg(const int* __restrict__ dst, int* __restrict__ cnt) {
    int e = blockIdx.x * 256 + threadIdx.x;
    atomicAdd(&cnt[dst[e]], 1);
}

// ---------------- 1/sqrt(deg), 1/deg ----------------
__global__ __launch_bounds__(256) void k_dinv(const int* __restrict__ cnt, float* __restrict__ d_isqrt,
                                              float* __restrict__ self_norm) {
    int i = blockIdx.x * 256 + threadIdx.x;
    float deg = (float)(1 + cnt[i]);
    float is = 1.0f / sqrtf(deg);
    d_isqrt[i] = is;
    self_norm[i] = is * is;
}

// ---------------- exclusive scan (3 kernels, 1024 elems/block) ----------------
__global__ __launch_bounds__(256) void k_scan1(const int* __restrict__ cnt, int* __restrict__ row_off,
                                               int* __restrict__ bsums) {
    __shared__ int ts[256];
    int tid = threadIdx.x;
    int base = blockIdx.x * 1024 + tid * 4;
    int v0 = cnt[base], v1 = cnt[base + 1], v2 = cnt[base + 2], v3 = cnt[base + 3];
    int s = v0 + v1 + v2 + v3;
    ts[tid] = s;
    __syncthreads();
    int inc = s;
    for (int off = 1; off < 256; off <<= 1) {
        int add = (tid >= off) ? ts[tid - off] : 0;
        __syncthreads();
        inc += add;
        ts[tid] = inc;
        __syncthreads();
    }
    int excl = inc - s;
    row_off[base] = excl;
    row_off[base + 1] = excl + v0;
    row_off[base + 2] = excl + v0 + v1;
    row_off[base + 3] = excl + v0 + v1 + v2;
    if (tid == 255) bsums[blockIdx.x] = inc;
}

__global__ __launch_bounds__(256) void k_scan2(int* __restrict__ bsums, int nb) {
    __shared__ int ts[256];
    int tid = threadIdx.x;
    int v = (tid < nb) ? bsums[tid] : 0;
    ts[tid] = v;
    __syncthreads();
    int inc = v;
    for (int off = 1; off < 256; off <<= 1) {
        int add = (tid >= off) ? ts[tid - off] : 0;
        __syncthreads();
        inc += add;
        ts[tid] = inc;
        __syncthreads();
    }
    if (tid < nb) bsums[tid] = inc - v;
}

__global__ __launch_bounds__(256) void k_scan3(int* __restrict__ row_off, const int* __restrict__ bsums) {
    int i = blockIdx.x * 256 + threadIdx.x;
    row_off[i] += bsums[i >> 10];
    if (i == 0) row_off[NN_TOT] = E_TOT;
}

// ---------------- CSR scatter (+ edge norm) ----------------
__global__ __launch_bounds__(256) void k_scatter(const int* __restrict__ src, const int* __restrict__ dst,
                                                 const float* __restrict__ d_isqrt, const int* __restrict__ row_off,
                                                 int* __restrict__ cursor, int* __restrict__ src_sorted,
                                                 float* __restrict__ en_sorted) {
    int e = blockIdx.x * 256 + threadIdx.x;
    int s = src[e], d = dst[e];
    float en = d_isqrt[s] * d_isqrt[d];
    int p = atomicAdd(&cursor[d], 1);
    int idx = row_off[d] + p;
    src_sorted[idx] = s;
    en_sorted[idx] = en;
}

// ---------------- GCN layer 0 fused: 3-dim aggregate + 3x128 matvec + relu ----------------
// one wave per node
__global__ __launch_bounds__(256) void k_gcn0(const float* __restrict__ x, const int* __restrict__ row_off,
                                              const int* __restrict__ src_sorted, const float* __restrict__ en_sorted,
                                              const float* __restrict__ self_norm, const float* __restrict__ W0,
                                              const float* __restrict__ b0, float* __restrict__ h0) {
    const int lane = threadIdx.x & 63;
    const int n = blockIdx.x * 4 + (threadIdx.x >> 6);
    float p0 = 0.f, p1 = 0.f, p2 = 0.f;
    const int beg = row_off[n], end = row_off[n + 1];
    for (int ei = beg + lane; ei < end; ei += 64) {
        int s = src_sorted[ei];
        float en = en_sorted[ei];
        p0 = fmaf(x[3 * s], en, p0);
        p1 = fmaf(x[3 * s + 1], en, p1);
        p2 = fmaf(x[3 * s + 2], en, p2);
    }
#pragma unroll
    for (int m = 32; m >= 1; m >>= 1) {
        p0 += __shfl_xor(p0, m);
        p1 += __shfl_xor(p1, m);
        p2 += __shfl_xor(p2, m);
    }
    const float sn = self_norm[n];
    const float z0 = fmaf(x[3 * n], sn, p0);
    const float z1 = fmaf(x[3 * n + 1], sn, p1);
    const float z2 = fmaf(x[3 * n + 2], sn, p2);
    const int j = lane * 2;
    float o0 = b0[j] + z0 * W0[j] + z1 * W0[128 + j] + z2 * W0[256 + j];
    float o1 = b0[j + 1] + z0 * W0[j + 1] + z1 * W0[128 + j + 1] + z2 * W0[256 + j + 1];
    float2 o;
    o.x = fmaxf(o0, 0.f);
    o.y = fmaxf(o1, 0.f);
    *(float2*)&h0[n * HID + j] = o;
}

// ---------------- 128-dim aggregation + self term -> z1 ----------------
// one wave per node; lane covers features 2*lane, 2*lane+1
__global__ __launch_bounds__(256) void k_agg(const float* __restrict__ h0, const int* __restrict__ row_off,
                                             const int* __restrict__ src_sorted, const float* __restrict__ en_sorted,
                                             const float* __restrict__ self_norm, float* __restrict__ z1out) {
    const int lane = threadIdx.x & 63;
    const int n = blockIdx.x * 4 + (threadIdx.x >> 6);
    const float2* h0v = (const float2*)h0;
    float2 acc;
    acc.x = 0.f;
    acc.y = 0.f;
    const int beg = row_off[n], end = row_off[n + 1];
    for (int ei = beg; ei < end; ++ei) {
        int s = src_sorted[ei];
        float en = en_sorted[ei];
        float2 v = h0v[s * 64 + lane];
        acc.x = fmaf(v.x, en, acc.x);
        acc.y = fmaf(v.y, en, acc.y);
    }
    float sn = self_norm[n];
    float2 hn = h0v[n * 64 + lane];
    float2 z;
    z.x = fmaf(hn.x, sn, acc.x);
    z.y = fmaf(hn.y, sn, acc.y);
    ((float2*)z1out)[n * 64 + lane] = z;
}

// ---------------- fp32 GEMM: C[M x 128] = relu(A[M x 128] @ B[128 x 128] + bias) ----------------
// block: 64 rows, 256 threads, 4x2 microtile, N split in four 32-col passes (LDS = 48 KB)
__global__ __launch_bounds__(256) void k_gemm_relu(const float* __restrict__ A, const float* __restrict__ Bw,
                                                   const float* __restrict__ bias, float* __restrict__ C) {
    __shared__ float As[128 * 64];  // [k][r]  32 KB
    __shared__ float Bs[128 * 32];  // [k][c]  16 KB (one N-quarter)
    const int tid = threadIdx.x;
    const int m0 = blockIdx.x * 64;
    {
        const int r = tid >> 2, kq = (tid & 3) << 5;
        const float* Ar = A + (size_t)(m0 + r) * 128 + kq;
#pragma unroll
        for (int i = 0; i < 8; ++i) {
            float4 v = *(const float4*)(Ar + i * 4);
            int k = kq + i * 4;
            As[(k + 0) * 64 + r] = v.x;
            As[(k + 1) * 64 + r] = v.y;
            As[(k + 2) * 64 + r] = v.z;
            As[(k + 3) * 64 + r] = v.w;
        }
    }
    const int r0 = (tid >> 4) << 2;  // 0..60
    const int c0 = (tid & 15) << 1;  // 0..30
    for (int nq = 0; nq < 4; ++nq) {
        __syncthreads();
        for (int i = tid * 4; i < 4096; i += 1024) {
            int k = i >> 5, c = i & 31;
            *(float4*)&Bs[i] = *(const float4*)&Bw[k * 128 + nq * 32 + c];
        }
        __syncthreads();
        float acc[4][2] = {{0.f}};
#pragma unroll 4
        for (int k = 0; k < 128; ++k) {
            float4 a4 = *(const float4*)&As[k * 64 + r0];
            float2 b2 = *(const float2*)&Bs[k * 32 + c0];
            acc[0][0] = fmaf(a4.x, b2.x, acc[0][0]);
            acc[0][1] = fmaf(a4.x, b2.y, acc[0][1]);
            acc[1][0] = fmaf(a4.y, b2.x, acc[1][0]);
            acc[1][1] = fmaf(a4.y, b2.y, acc[1][1]);
            acc[2][0] = fmaf(a4.z, b2.x, acc[2][0]);
            acc[2][1] = fmaf(a4.z, b2.y, acc[2][1]);
            acc[3][0] = fmaf(a4.w, b2.x, acc[3][0]);
            acc[3][1] = fmaf(a4.w, b2.y, acc[3][1]);
        }
        const float2 bi = *(const float2*)&bias[nq * 32 + c0];
#pragma unroll
        for (int i = 0; i < 4; ++i) {
            float2 o;
            o.x = fmaxf(acc[i][0] + bi.x, 0.f);
            o.y = fmaxf(acc[i][1] + bi.y, 0.f);
            *(float2*)&C[(size_t)(m0 + r0 + i) * 128 + nq * 32 + c0] = o;
        }
    }
}

// ---------------- weight transposes for GRU (both fp32) ----------------
__global__ __launch_bounds__(256) void k_transpose(const float* __restrict__ Wih, const float* __restrict__ Whh,
                                                   float* __restrict__ WihT, float* __restrict__ WhhT) {
    int i = blockIdx.x * 256 + threadIdx.x;  // over 384*128
    int o = i >> 7, k = i & 127;
    WihT[k * 384 + o] = Wih[i];
    WhhT[k * 384 + o] = Whh[i];
}

// ---------------- frame pooling + gi precompute ----------------
// block per (b,t): mean over 68 nodes, then GI[bt][0..383] = frames @ W_ih^T + b_ih
__global__ __launch_bounds__(128) void k_pool_gi(const float* __restrict__ h2, const float* __restrict__ WihT,
                                                 const float* __restrict__ bih, float* __restrict__ GI) {
    __shared__ float fr[128];
    const int bt = blockIdx.x, j = threadIdx.x;
    const float* base = h2 + (size_t)bt * NPF * HID;
    float s = 0.f;
    for (int n = 0; n < NPF; ++n) s += base[n * HID + j];
    fr[j] = s * (1.0f / NPF);
    __syncthreads();
#pragma unroll
    for (int p = 0; p < 3; ++p) {
        int o = j + p * 128;
        float a = bih[o];
#pragma unroll 8
        for (int k = 0; k < 128; ++k) a = fmaf(fr[k], WihT[k * 384 + o], a);
        GI[bt * 384 + o] = a;
    }
}

// ---------------- GRU recurrence: one block per batch, W_hh^T rows in fp32 registers ----------------
__global__ __launch_bounds__(384) void k_gru(const float* __restrict__ GI, const float* __restrict__ WhhT,
                                             const float* __restrict__ bhh, float* __restrict__ hT) {
    __shared__ float hc[128];
    __shared__ float ghs[384];
    const int tid = threadIdx.x;
    const int b = blockIdx.x;
    float4 w[32];
#pragma unroll
    for (int k4 = 0; k4 < 32; ++k4) {
        w[k4].x = WhhT[(4 * k4 + 0) * 384 + tid];
        w[k4].y = WhhT[(4 * k4 + 1) * 384 + tid];
        w[k4].z = WhhT[(4 * k4 + 2) * 384 + tid];
        w[k4].w = WhhT[(4 * k4 + 3) * 384 + tid];
    }
    if (tid < 128) hc[tid] = 0.f;
    const float bh = bhh[tid];
    __syncthreads();
    for (int t = 0; t < T_SZ; ++t) {
        float a0 = bh, a1 = 0.f, a2 = 0.f, a3 = 0.f;
        const float4* h4 = (const float4*)hc;
#pragma unroll
        for (int k4 = 0; k4 < 32; ++k4) {
            float4 hv = h4[k4];
            a0 = fmaf(w[k4].x, hv.x, a0);
            a1 = fmaf(w[k4].y, hv.y, a1);
            a2 = fmaf(w[k4].z, hv.z, a2);
            a3 = fmaf(w[k4].w, hv.w, a3);
        }
        ghs[tid] = (a0 + a1) + (a2 + a3);
        __syncthreads();
        if (tid < 128) {
            const float* gi = GI + (size_t)(b * T_SZ + t) * 384;
            float ir = gi[tid], iz = gi[128 + tid], inn = gi[256 + tid];
            float hrv = ghs[tid], hz = ghs[128 + tid], hn = ghs[256 + tid];
            float r = 1.f / (1.f + expf(-(ir + hrv)));
            float z = 1.f / (1.f + expf(-(iz + hz)));
            float nn = tanhf(inn + r * hn);
            float hnew = (1.f - z) * nn + z * hc[tid];
            hc[tid] = hnew;
        }
        __syncthreads();
    }
    if (tid < 128) hT[b * 128 + tid] = hc[tid];
}

// ---------------- classifier head (384 threads: phase 2 needs 320!) ----------------
__global__ __launch_bounds__(384) void k_cls(const float* __restrict__ hT, const float* __restrict__ Wc1,
                                             const float* __restrict__ bc1, const float* __restrict__ Wc2,
                                             const float* __restrict__ bc2, float* __restrict__ out) {
    __shared__ float hid[32 * 64];
    int tid = threadIdx.x;
    for (int idx = tid; idx < 2048; idx += 384) {
        int b = idx >> 6, j = idx & 63;
        float a = bc1[j];
#pragma unroll 8
        for (int k = 0; k < 128; ++k) a = fmaf(hT[b * 128 + k], Wc1[k * 64 + j], a);
        hid[idx] = fmaxf(a, 0.f);
    }
    __syncthreads();
    if (tid < 320) {
        int b = tid / 10, c = tid % 10;
        float a = bc2[c];
#pragma unroll 8
        for (int k = 0; k < 64; ++k) a = fmaf(hid[b * 64 + k], Wc2[k * 10 + c], a);
        out[tid] = a;
    }
}

extern "C" void kernel_launch(void* const* d_in, const int* in_sizes, int n_in, void* d_out, int out_size, void* d_ws,
                              size_t ws_size, hipStream_t stream) {
    const float* x = (const float*)d_in[0];
    const int* ei = (const int*)d_in[1];
    const int* e_src = ei;
    const int* e_dst = ei + E_TOT;
    const float* W0 = (const float*)d_in[2];
    const float* b0 = (const float*)d_in[3];
    const float* W1 = (const float*)d_in[4];
    const float* b1 = (const float*)d_in[5];
    const float* Wm = (const float*)d_in[6];
    const float* bm = (const float*)d_in[7];
    const float* Wih = (const float*)d_in[8];
    const float* Whh = (const float*)d_in[9];
    const float* bih = (const float*)d_in[10];
    const float* bhh = (const float*)d_in[11];
    const float* Wc1 = (const float*)d_in[12];
    const float* bc1 = (const float*)d_in[13];
    const float* Wc2 = (const float*)d_in[14];
    const float* bc2 = (const float*)d_in[15];
    float* out = (float*)d_out;

    char* base = (char*)d_ws;
    size_t off = 0;
    auto alloc = [&](size_t bytes) {
        size_t o = off;
        off = (off + bytes + 255) & ~(size_t)255;
        return o;
    };
    size_t o_cnt = alloc((size_t)NN_TOT * 4);
    size_t o_cursor = alloc((size_t)NN_TOT * 4);  // contiguous with cnt for one memset
    size_t o_rowoff = alloc((size_t)(NN_TOT + 1) * 4);
    size_t o_bsums = alloc(256 * 4);
    size_t o_disqrt = alloc((size_t)NN_TOT * 4);
    size_t o_snorm = alloc((size_t)NN_TOT * 4);
    size_t o_srcs = alloc((size_t)E_TOT * 4);
    size_t o_ens = alloc((size_t)E_TOT * 4);
    size_t o_gi = alloc((size_t)B_SZ * T_SZ * 384 * 4);
    size_t o_wiht = alloc((size_t)128 * 384 * 4);
    size_t o_whht = alloc((size_t)128 * 384 * 4);
    size_t o_ht = alloc((size_t)B_SZ * 128 * 4);
    size_t o_bufA = alloc((size_t)NN_TOT * HID * 4);
    size_t o_bufB = alloc((size_t)NN_TOT * HID * 4);
    if (off > ws_size) return;  // workspace too small -> visible validation failure

    int* cnt = (int*)(base + o_cnt);
    int* cursor = (int*)(base + o_cursor);
    int* row_off = (int*)(base + o_rowoff);
    int* bsums = (int*)(base + o_bsums);
    float* d_isqrt = (float*)(base + o_disqrt);
    float* self_norm = (float*)(base + o_snorm);
    int* src_sorted = (int*)(base + o_srcs);
    float* en_sorted = (float*)(base + o_ens);
    float* GI = (float*)(base + o_gi);
    float* WihT = (float*)(base + o_wiht);
    float* WhhT = (float*)(base + o_whht);
    float* hT = (float*)(base + o_ht);
    float* bufA = (float*)(base + o_bufA);  // h0, then h1
    float* bufB = (float*)(base + o_bufB);  // z1, then h2

    hipMemsetAsync(base + o_cnt, 0, (size_t)2 * NN_TOT * 4, stream);  // cnt + cursor

    k_deg<<<E_TOT / 256, 256, 0, stream>>>(e_dst, cnt);
    k_dinv<<<NN_TOT / 256, 256, 0, stream>>>(cnt, d_isqrt, self_norm);
    k_scan1<<<NN_TOT / 1024, 256, 0, stream>>>(cnt, row_off, bsums);
    k_scan2<<<1, 256, 0, stream>>>(bsums, NN_TOT / 1024);
    k_scan3<<<NN_TOT / 256, 256, 0, stream>>>(row_off, bsums);
    k_scatter<<<E_TOT / 256, 256, 0, stream>>>(e_src, e_dst, d_isqrt, row_off, cursor, src_sorted, en_sorted);
    k_gcn0<<<NN_TOT / 4, 256, 0, stream>>>(x, row_off, src_sorted, en_sorted, self_norm, W0, b0, bufA);
    k_agg<<<NN_TOT / 4, 256, 0, stream>>>(bufA, row_off, src_sorted, en_sorted, self_norm, bufB);
    k_gemm_relu<<<NN_TOT / 64, 256, 0, stream>>>(bufB, W1, b1, bufA);  // z1 -> h1
    k_gemm_relu<<<NN_TOT / 64, 256, 0, stream>>>(bufA, Wm, bm, bufB);  // h1 -> h2
    k_transpose<<<(384 * 128) / 256, 256, 0, stream>>>(Wih, Whh, WihT, WhhT);
    k_pool_gi<<<B_SZ * T_SZ, 128, 0, stream>>>(bufB, WihT, bih, GI);
    k_gru<<<B_SZ, 384, 0, stream>>>(GI, WhhT, bhh, hT);
    k_cls<<<1, 384, 0, stream>>>(hT, Wc1, bc1, Wc2, bc2, out);
}

// Round 4
// 725.815 us; speedup vs baseline: 1.3630x; 1.3630x over previous
//
#include <hip/hip_runtime.h>

#define NN_TOT 208896      // 32*96*68 nodes
#define E_TOT  1671168     // NN_TOT*8 edges
#define B_SZ   32
#define T_SZ   96
#define NPF    68          // nodes per frame
#define HID    128

typedef _Float16 f16x8 __attribute__((ext_vector_type(8)));
typedef _Float16 f16x2v __attribute__((ext_vector_type(2)));
typedef float f32x4 __attribute__((ext_vector_type(4)));

// ---------------- degree count ----------------
__global__ __launch_bounds__(256) void k_deg(const int* __restrict__ dst, int* __restrict__ cnt) {
    int e = blockIdx.x * 256 + threadIdx.x;
    atomicAdd(&cnt[dst[e]], 1);
}

// ---------------- 1/sqrt(deg), 1/deg ----------------
__global__ __launch_bounds__(256) void k_dinv(const int* __restrict__ cnt, float* __restrict__ d_isqrt,
                                              float* __restrict__ self_norm) {
    int i = blockIdx.x * 256 + threadIdx.x;
    float deg = (float)(1 + cnt[i]);
    float is = 1.0f / sqrtf(deg);
    d_isqrt[i] = is;
    self_norm[i] = is * is;
}

// ---------------- exclusive scan (3 kernels, 1024 elems/block) ----------------
__global__ __launch_bounds__(256) void k_scan1(const int* __restrict__ cnt, int* __restrict__ row_off,
                                               int* __restrict__ bsums) {
    __shared__ int ts[256];
    int tid = threadIdx.x;
    int base = blockIdx.x * 1024 + tid * 4;
    int v0 = cnt[base], v1 = cnt[base + 1], v2 = cnt[base + 2], v3 = cnt[base + 3];
    int s = v0 + v1 + v2 + v3;
    ts[tid] = s;
    __syncthreads();
    int inc = s;
    for (int off = 1; off < 256; off <<= 1) {
        int add = (tid >= off) ? ts[tid - off] : 0;
        __syncthreads();
        inc += add;
        ts[tid] = inc;
        __syncthreads();
    }
    int excl = inc - s;
    row_off[base] = excl;
    row_off[base + 1] = excl + v0;
    row_off[base + 2] = excl + v0 + v1;
    row_off[base + 3] = excl + v0 + v1 + v2;
    if (tid == 255) bsums[blockIdx.x] = inc;
}

__global__ __launch_bounds__(256) void k_scan2(int* __restrict__ bsums, int nb) {
    __shared__ int ts[256];
    int tid = threadIdx.x;
    int v = (tid < nb) ? bsums[tid] : 0;
    ts[tid] = v;
    __syncthreads();
    int inc = v;
    for (int off = 1; off < 256; off <<= 1) {
        int add = (tid >= off) ? ts[tid - off] : 0;
        __syncthreads();
        inc += add;
        ts[tid] = inc;
        __syncthreads();
    }
    if (tid < nb) bsums[tid] = inc - v;
}

__global__ __launch_bounds__(256) void k_scan3(int* __restrict__ row_off, const int* __restrict__ bsums) {
    int i = blockIdx.x * 256 + threadIdx.x;
    row_off[i] += bsums[i >> 10];
    if (i == 0) row_off[NN_TOT] = E_TOT;
}

// ---------------- CSR scatter (+ edge norm) ----------------
__global__ __launch_bounds__(256) void k_scatter(const int* __restrict__ src, const int* __restrict__ dst,
                                                 const float* __restrict__ d_isqrt, const int* __restrict__ row_off,
                                                 int* __restrict__ cursor, int* __restrict__ src_sorted,
                                                 float* __restrict__ en_sorted) {
    int e = blockIdx.x * 256 + threadIdx.x;
    int s = src[e], d = dst[e];
    float en = d_isqrt[s] * d_isqrt[d];
    int p = atomicAdd(&cursor[d], 1);
    int idx = row_off[d] + p;
    src_sorted[idx] = s;
    en_sorted[idx] = en;
}

// ---------------- weight prep: GRU transposes (f32) + MFMA fragment packs (f16) ----------------
// pack layout: W*p[((j*4+kk)*64 + lane)*8 + e] = W[kk*32 + (lane>>4)*8 + e][j*16 + (lane&15)]
__global__ __launch_bounds__(256) void k_prep(const float* __restrict__ Wih, const float* __restrict__ Whh,
                                              const float* __restrict__ W1, const float* __restrict__ Wm,
                                              float* __restrict__ WihT, float* __restrict__ WhhT,
                                              _Float16* __restrict__ W1p, _Float16* __restrict__ Wmp) {
    int i = blockIdx.x * 256 + threadIdx.x;  // 0..49151
    {
        int o = i >> 7, k = i & 127;
        WihT[k * 384 + o] = Wih[i];
        WhhT[k * 384 + o] = Whh[i];
    }
    if (i < 16384) {
        int f = i >> 9;          // frag id 0..31
        int j = f >> 2, kk = f & 3;
        int lane = (i >> 3) & 63;
        int e = i & 7;
        int q = lane >> 4, p = lane & 15;
        int k = kk * 32 + q * 8 + e, n = j * 16 + p;
        W1p[i] = (_Float16)W1[k * 128 + n];
        Wmp[i] = (_Float16)Wm[k * 128 + n];
    }
}

// ---------------- GCN layer 0 fused: 3-dim aggregate + 3x128 matvec + relu -> h0 (f16) ----------------
// one wave per node
__global__ __launch_bounds__(256) void k_gcn0(const float* __restrict__ x, const int* __restrict__ row_off,
                                              const int* __restrict__ src_sorted, const float* __restrict__ en_sorted,
                                              const float* __restrict__ self_norm, const float* __restrict__ W0,
                                              const float* __restrict__ b0, _Float16* __restrict__ h0) {
    const int lane = threadIdx.x & 63;
    const int n = blockIdx.x * 4 + (threadIdx.x >> 6);
    float p0 = 0.f, p1 = 0.f, p2 = 0.f;
    const int beg = row_off[n], end = row_off[n + 1];
    for (int ei = beg + lane; ei < end; ei += 64) {
        int s = src_sorted[ei];
        float en = en_sorted[ei];
        p0 = fmaf(x[3 * s], en, p0);
        p1 = fmaf(x[3 * s + 1], en, p1);
        p2 = fmaf(x[3 * s + 2], en, p2);
    }
#pragma unroll
    for (int m = 32; m >= 1; m >>= 1) {
        p0 += __shfl_xor(p0, m);
        p1 += __shfl_xor(p1, m);
        p2 += __shfl_xor(p2, m);
    }
    const float sn = self_norm[n];
    const float z0 = fmaf(x[3 * n], sn, p0);
    const float z1 = fmaf(x[3 * n + 1], sn, p1);
    const float z2 = fmaf(x[3 * n + 2], sn, p2);
    const int j = lane * 2;
    float o0 = b0[j] + z0 * W0[j] + z1 * W0[128 + j] + z2 * W0[256 + j];
    float o1 = b0[j + 1] + z0 * W0[j + 1] + z1 * W0[128 + j + 1] + z2 * W0[256 + j + 1];
    f16x2v o;
    o[0] = (_Float16)fmaxf(o0, 0.f);
    o[1] = (_Float16)fmaxf(o1, 0.f);
    *(f16x2v*)(h0 + (size_t)n * HID + j) = o;
}

// ---------------- fused: 128-dim aggregation (f16 gather) + GEMM1 (f16 MFMA) + relu -> h1 (f16) ----
// 64 nodes per block, 4 waves, wave w owns nodes w*16..w*16+15 (= its MFMA m-tile).
__global__ __launch_bounds__(256) void k_agg_mm(const _Float16* __restrict__ h0, const int* __restrict__ row_off,
                                                const int* __restrict__ src_sorted, const float* __restrict__ en_sorted,
                                                const float* __restrict__ self_norm, const _Float16* __restrict__ W1p,
                                                const float* __restrict__ b1, _Float16* __restrict__ h1) {
    __shared__ _Float16 As[64 * 136];  // rows padded to 136 f16 (272 B, 16B-aligned)
    const int tid = threadIdx.x;
    const int w = tid >> 6, lane = tid & 63;
    const int q = lane >> 4, c = lane & 15;
    const int blk = blockIdx.x;
    const f16x8* __restrict__ h0v = (const f16x8*)h0;

    // phase 1: aggregate 16 nodes, 4 edges in flight (one per quarter-wave)
    for (int i = 0; i < 16; ++i) {
        const int node = blk * 64 + w * 16 + i;
        const int beg = row_off[node], end = row_off[node + 1];
        float acc[8] = {0.f, 0.f, 0.f, 0.f, 0.f, 0.f, 0.f, 0.f};
        for (int ei = beg; ei < end; ei += 4) {
            int e = ei + q;
            int ec = min(e, end - 1);
            int s = src_sorted[ec];
            float en = (e < end) ? en_sorted[ec] : 0.f;
            f16x8 v = h0v[s * 16 + c];
#pragma unroll
            for (int k = 0; k < 8; ++k) acc[k] = fmaf((float)v[k], en, acc[k]);
        }
#pragma unroll
        for (int k = 0; k < 8; ++k) {
            acc[k] += __shfl_xor(acc[k], 16);
            acc[k] += __shfl_xor(acc[k], 32);
        }
        const float sn = self_norm[node];
        f16x8 sv = h0v[node * 16 + c];
        f16x8 o;
#pragma unroll
        for (int k = 0; k < 8; ++k) o[k] = (_Float16)fmaf((float)sv[k], sn, acc[k]);
        if (q == 0) *(f16x8*)(&As[(w * 16 + i) * 136 + c * 8]) = o;
    }
    __syncthreads();

    // phase 2: MFMA 16x128x128, A-frags from own rows
    f16x8 afr[4];
#pragma unroll
    for (int kk = 0; kk < 4; ++kk) afr[kk] = *(const f16x8*)(&As[(w * 16 + c) * 136 + kk * 32 + q * 8]);
    const f16x8* __restrict__ Bv = (const f16x8*)W1p;
    _Float16* Cst = &As[w * 2176];  // reuse own As region for C staging ([16][128] f16)
#pragma unroll
    for (int j = 0; j < 8; ++j) {
        f32x4 cc = {0.f, 0.f, 0.f, 0.f};
#pragma unroll
        for (int kk = 0; kk < 4; ++kk)
            cc = __builtin_amdgcn_mfma_f32_16x16x32_f16(afr[kk], Bv[(j * 4 + kk) * 64 + lane], cc, 0, 0, 0);
        const float bi = b1[j * 16 + c];
#pragma unroll
        for (int r = 0; r < 4; ++r) Cst[(q * 4 + r) * 128 + j * 16 + c] = (_Float16)fmaxf(cc[r] + bi, 0.f);
    }
    // phase 3: coalesced store of own 16 rows
#pragma unroll
    for (int it = 0; it < 4; ++it) {
        int idx = it * 64 + lane;
        *(f16x8*)(h1 + (size_t)(blk * 64 + w * 16) * 128 + idx * 8) = *(const f16x8*)(&As[w * 2176 + idx * 8]);
    }
}

// ---------------- fused: GEMM2 (f16 MFMA) + relu + frame mean + gi precompute ----------------
// one block per (b,t) frame: 68 rows. m-tiles 0..4 (tile 4 rows 68..79 zero-padded, masked from mean).
__global__ __launch_bounds__(256) void k_mm_pool(const _Float16* __restrict__ h1, const _Float16* __restrict__ Wmp,
                                                 const float* __restrict__ bm, const float* __restrict__ WihT,
                                                 const float* __restrict__ bih, float* __restrict__ GI) {
    __shared__ _Float16 As[80 * 136];
    __shared__ float colpart[4 * 128];
    __shared__ float fr[128];
    const int tid = threadIdx.x;
    const int w = tid >> 6, lane = tid & 63;
    const int q = lane >> 4, c = lane & 15;
    const int bt = blockIdx.x;

    const f16x8* __restrict__ srcv = (const f16x8*)(h1 + (size_t)bt * NPF * HID);
    for (int idx = tid; idx < 80 * 17; idx += 256) {
        int row = idx / 17, ch = idx % 17;
        f16x8 v;
        if (row < NPF && ch < 16) {
            v = srcv[row * 16 + ch];
        } else {
#pragma unroll
            for (int k = 0; k < 8; ++k) v[k] = (_Float16)0.f;
        }
        *(f16x8*)(&As[row * 136 + ch * 8]) = v;
    }
    __syncthreads();

    const f16x8* __restrict__ Bv = (const f16x8*)Wmp;
    const int npass = (w == 0) ? 2 : 1;
    for (int pass = 0; pass < npass; ++pass) {
        const int mt = pass ? 4 : w;
        f16x8 afr[4];
#pragma unroll
        for (int kk = 0; kk < 4; ++kk) afr[kk] = *(const f16x8*)(&As[(mt * 16 + c) * 136 + kk * 32 + q * 8]);
#pragma unroll
        for (int j = 0; j < 8; ++j) {
            f32x4 cc = {0.f, 0.f, 0.f, 0.f};
#pragma unroll
            for (int kk = 0; kk < 4; ++kk)
                cc = __builtin_amdgcn_mfma_f32_16x16x32_f16(afr[kk], Bv[(j * 4 + kk) * 64 + lane], cc, 0, 0, 0);
            const float bi = bm[j * 16 + c];
            float s = 0.f;
#pragma unroll
            for (int r = 0; r < 4; ++r) {
                int m = mt * 16 + q * 4 + r;
                float v = fmaxf(cc[r] + bi, 0.f);
                s += (m < NPF) ? v : 0.f;
            }
            s += __shfl_xor(s, 16);
            s += __shfl_xor(s, 32);
            if (lane < 16) {
                float* dst = &colpart[w * 128 + j * 16 + c];
                *dst = (pass == 0) ? s : (*dst + s);
            }
        }
    }
    __syncthreads();
    if (tid < 128)
        fr[tid] = (colpart[tid] + colpart[128 + tid] + colpart[256 + tid] + colpart[384 + tid]) * (1.0f / NPF);
    __syncthreads();
    if (tid < 128) {
#pragma unroll
        for (int p = 0; p < 3; ++p) {
            int o = tid + p * 128;
            float a = bih[o];
#pragma unroll 8
            for (int k = 0; k < 128; ++k) a = fmaf(fr[k], WihT[k * 384 + o], a);
            GI[(size_t)bt * 384 + o] = a;
        }
    }
}

// ---------------- GRU recurrence: one block per batch, W_hh^T rows in fp32 registers ----------------
__global__ __launch_bounds__(384) void k_gru(const float* __restrict__ GI, const float* __restrict__ WhhT,
                                             const float* __restrict__ bhh, float* __restrict__ hT) {
    __shared__ float hc[128];
    __shared__ float ghs[384];
    const int tid = threadIdx.x;
    const int b = blockIdx.x;
    float4 w[32];
#pragma unroll
    for (int k4 = 0; k4 < 32; ++k4) {
        w[k4].x = WhhT[(4 * k4 + 0) * 384 + tid];
        w[k4].y = WhhT[(4 * k4 + 1) * 384 + tid];
        w[k4].z = WhhT[(4 * k4 + 2) * 384 + tid];
        w[k4].w = WhhT[(4 * k4 + 3) * 384 + tid];
    }
    if (tid < 128) hc[tid] = 0.f;
    const float bh = bhh[tid];
    __syncthreads();
    for (int t = 0; t < T_SZ; ++t) {
        float a0 = bh, a1 = 0.f, a2 = 0.f, a3 = 0.f;
        const float4* h4 = (const float4*)hc;
#pragma unroll
        for (int k4 = 0; k4 < 32; ++k4) {
            float4 hv = h4[k4];
            a0 = fmaf(w[k4].x, hv.x, a0);
            a1 = fmaf(w[k4].y, hv.y, a1);
            a2 = fmaf(w[k4].z, hv.z, a2);
            a3 = fmaf(w[k4].w, hv.w, a3);
        }
        ghs[tid] = (a0 + a1) + (a2 + a3);
        __syncthreads();
        if (tid < 128) {
            const float* gi = GI + (size_t)(b * T_SZ + t) * 384;
            float ir = gi[tid], iz = gi[128 + tid], inn = gi[256 + tid];
            float hrv = ghs[tid], hz = ghs[128 + tid], hn = ghs[256 + tid];
            float r = 1.f / (1.f + expf(-(ir + hrv)));
            float z = 1.f / (1.f + expf(-(iz + hz)));
            float nn = tanhf(inn + r * hn);
            float hnew = (1.f - z) * nn + z * hc[tid];
            hc[tid] = hnew;
        }
        __syncthreads();
    }
    if (tid < 128) hT[b * 128 + tid] = hc[tid];
}

// ---------------- classifier head (384 threads: phase 2 needs 320) ----------------
__global__ __launch_bounds__(384) void k_cls(const float* __restrict__ hT, const float* __restrict__ Wc1,
                                             const float* __restrict__ bc1, const float* __restrict__ Wc2,
                                             const float* __restrict__ bc2, float* __restrict__ out) {
    __shared__ float hid[32 * 64];
    int tid = threadIdx.x;
    for (int idx = tid; idx < 2048; idx += 384) {
        int b = idx >> 6, j = idx & 63;
        float a = bc1[j];
#pragma unroll 8
        for (int k = 0; k < 128; ++k) a = fmaf(hT[b * 128 + k], Wc1[k * 64 + j], a);
        hid[idx] = fmaxf(a, 0.f);
    }
    __syncthreads();
    if (tid < 320) {
        int b = tid / 10, c = tid % 10;
        float a = bc2[c];
#pragma unroll 8
        for (int k = 0; k < 64; ++k) a = fmaf(hid[b * 64 + k], Wc2[k * 10 + c], a);
        out[tid] = a;
    }
}

extern "C" void kernel_launch(void* const* d_in, const int* in_sizes, int n_in, void* d_out, int out_size, void* d_ws,
                              size_t ws_size, hipStream_t stream) {
    const float* x = (const float*)d_in[0];
    const int* ei = (const int*)d_in[1];
    const int* e_src = ei;
    const int* e_dst = ei + E_TOT;
    const float* W0 = (const float*)d_in[2];
    const float* b0 = (const float*)d_in[3];
    const float* W1 = (const float*)d_in[4];
    const float* b1 = (const float*)d_in[5];
    const float* Wm = (const float*)d_in[6];
    const float* bm = (const float*)d_in[7];
    const float* Wih = (const float*)d_in[8];
    const float* Whh = (const float*)d_in[9];
    const float* bih = (const float*)d_in[10];
    const float* bhh = (const float*)d_in[11];
    const float* Wc1 = (const float*)d_in[12];
    const float* bc1 = (const float*)d_in[13];
    const float* Wc2 = (const float*)d_in[14];
    const float* bc2 = (const float*)d_in[15];
    float* out = (float*)d_out;

    char* base = (char*)d_ws;
    size_t off = 0;
    auto alloc = [&](size_t bytes) {
        size_t o = off;
        off = (off + bytes + 255) & ~(size_t)255;
        return o;
    };
    size_t o_cnt = alloc((size_t)NN_TOT * 4);
    size_t o_cursor = alloc((size_t)NN_TOT * 4);  // contiguous with cnt for one memset
    size_t o_rowoff = alloc((size_t)(NN_TOT + 1) * 4);
    size_t o_bsums = alloc(256 * 4);
    size_t o_disqrt = alloc((size_t)NN_TOT * 4);
    size_t o_snorm = alloc((size_t)NN_TOT * 4);
    size_t o_srcs = alloc((size_t)E_TOT * 4);
    size_t o_ens = alloc((size_t)E_TOT * 4);
    size_t o_gi = alloc((size_t)B_SZ * T_SZ * 384 * 4);
    size_t o_wiht = alloc((size_t)128 * 384 * 4);
    size_t o_whht = alloc((size_t)128 * 384 * 4);
    size_t o_w1p = alloc((size_t)128 * 128 * 2);
    size_t o_wmp = alloc((size_t)128 * 128 * 2);
    size_t o_ht = alloc((size_t)B_SZ * 128 * 4);
    size_t o_h0 = alloc((size_t)NN_TOT * HID * 2);
    size_t o_h1 = alloc((size_t)NN_TOT * HID * 2);
    if (off > ws_size) return;  // workspace too small -> visible validation failure

    int* cnt = (int*)(base + o_cnt);
    int* cursor = (int*)(base + o_cursor);
    int* row_off = (int*)(base + o_rowoff);
    int* bsums = (int*)(base + o_bsums);
    float* d_isqrt = (float*)(base + o_disqrt);
    float* self_norm = (float*)(base + o_snorm);
    int* src_sorted = (int*)(base + o_srcs);
    float* en_sorted = (float*)(base + o_ens);
    float* GI = (float*)(base + o_gi);
    float* WihT = (float*)(base + o_wiht);
    float* WhhT = (float*)(base + o_whht);
    _Float16* W1p = (_Float16*)(base + o_w1p);
    _Float16* Wmp = (_Float16*)(base + o_wmp);
    float* hT = (float*)(base + o_ht);
    _Float16* h0 = (_Float16*)(base + o_h0);
    _Float16* h1 = (_Float16*)(base + o_h1);

    hipMemsetAsync(base + o_cnt, 0, (size_t)2 * NN_TOT * 4, stream);  // cnt + cursor

    k_deg<<<E_TOT / 256, 256, 0, stream>>>(e_dst, cnt);
    k_dinv<<<NN_TOT / 256, 256, 0, stream>>>(cnt, d_isqrt, self_norm);
    k_scan1<<<NN_TOT / 1024, 256, 0, stream>>>(cnt, row_off, bsums);
    k_scan2<<<1, 256, 0, stream>>>(bsums, NN_TOT / 1024);
    k_scan3<<<NN_TOT / 256, 256, 0, stream>>>(row_off, bsums);
    k_scatter<<<E_TOT / 256, 256, 0, stream>>>(e_src, e_dst, d_isqrt, row_off, cursor, src_sorted, en_sorted);
    k_prep<<<(384 * 128) / 256, 256, 0, stream>>>(Wih, Whh, W1, Wm, WihT, WhhT, W1p, Wmp);
    k_gcn0<<<NN_TOT / 4, 256, 0, stream>>>(x, row_off, src_sorted, en_sorted, self_norm, W0, b0, h0);
    k_agg_mm<<<NN_TOT / 64, 256, 0, stream>>>(h0, row_off, src_sorted, en_sorted, self_norm, W1p, b1, h1);
    k_mm_pool<<<B_SZ * T_SZ, 256, 0, stream>>>(h1, Wmp, bm, WihT, bih, GI);
    k_gru<<<B_SZ, 384, 0, stream>>>(GI, WhhT, bhh, hT);
    k_cls<<<1, 384, 0, stream>>>(hT, Wc1, bc1, Wc2, bc2, out);
}

// Round 5
// 627.211 us; speedup vs baseline: 1.5773x; 1.1572x over previous
//
#include <hip/hip_runtime.h>

#define NN_TOT 208896      // 32*96*68 nodes
#define E_TOT  1671168     // NN_TOT*8 edges
#define B_SZ   32
#define T_SZ   96
#define NPF    68          // nodes per frame
#define HID    128

typedef _Float16 f16x8 __attribute__((ext_vector_type(8)));
typedef _Float16 f16x2v __attribute__((ext_vector_type(2)));
typedef float f32x4 __attribute__((ext_vector_type(4)));

// ---------------- degree count ----------------
__global__ __launch_bounds__(256) void k_deg(const int* __restrict__ dst, int* __restrict__ cnt) {
    int e = blockIdx.x * 256 + threadIdx.x;
    atomicAdd(&cnt[dst[e]], 1);
}

// ---------------- 1/sqrt(deg), 1/deg ----------------
__global__ __launch_bounds__(256) void k_dinv(const int* __restrict__ cnt, float* __restrict__ d_isqrt,
                                              float* __restrict__ self_norm) {
    int i = blockIdx.x * 256 + threadIdx.x;
    float deg = (float)(1 + cnt[i]);
    float is = 1.0f / sqrtf(deg);
    d_isqrt[i] = is;
    self_norm[i] = is * is;
}

// ---------------- exclusive scan (3 kernels, 1024 elems/block) ----------------
__global__ __launch_bounds__(256) void k_scan1(const int* __restrict__ cnt, int* __restrict__ row_off,
                                               int* __restrict__ bsums) {
    __shared__ int ts[256];
    int tid = threadIdx.x;
    int base = blockIdx.x * 1024 + tid * 4;
    int v0 = cnt[base], v1 = cnt[base + 1], v2 = cnt[base + 2], v3 = cnt[base + 3];
    int s = v0 + v1 + v2 + v3;
    ts[tid] = s;
    __syncthreads();
    int inc = s;
    for (int off = 1; off < 256; off <<= 1) {
        int add = (tid >= off) ? ts[tid - off] : 0;
        __syncthreads();
        inc += add;
        ts[tid] = inc;
        __syncthreads();
    }
    int excl = inc - s;
    row_off[base] = excl;
    row_off[base + 1] = excl + v0;
    row_off[base + 2] = excl + v0 + v1;
    row_off[base + 3] = excl + v0 + v1 + v2;
    if (tid == 255) bsums[blockIdx.x] = inc;
}

__global__ __launch_bounds__(256) void k_scan2(int* __restrict__ bsums, int nb) {
    __shared__ int ts[256];
    int tid = threadIdx.x;
    int v = (tid < nb) ? bsums[tid] : 0;
    ts[tid] = v;
    __syncthreads();
    int inc = v;
    for (int off = 1; off < 256; off <<= 1) {
        int add = (tid >= off) ? ts[tid - off] : 0;
        __syncthreads();
        inc += add;
        ts[tid] = inc;
        __syncthreads();
    }
    if (tid < nb) bsums[tid] = inc - v;
}

__global__ __launch_bounds__(256) void k_scan3(int* __restrict__ row_off, const int* __restrict__ bsums) {
    int i = blockIdx.x * 256 + threadIdx.x;
    row_off[i] += bsums[i >> 10];
    if (i == 0) row_off[NN_TOT] = E_TOT;
}

// ---------------- CSR scatter: packed (src, norm) int2 ----------------
__global__ __launch_bounds__(256) void k_scatter(const int* __restrict__ src, const int* __restrict__ dst,
                                                 const float* __restrict__ d_isqrt, const int* __restrict__ row_off,
                                                 int* __restrict__ cursor, int2* __restrict__ er) {
    int e = blockIdx.x * 256 + threadIdx.x;
    int s = src[e], d = dst[e];
    float en = d_isqrt[s] * d_isqrt[d];
    int p = atomicAdd(&cursor[d], 1);
    int idx = row_off[d] + p;
    er[idx] = make_int2(s, __float_as_int(en));
}

// ---------------- GCN layer 0: 64 nodes/block, 4 edge-slots/node, then block matvec ----------------
__global__ __launch_bounds__(256) void k_gcn0(const float* __restrict__ x, const int* __restrict__ row_off,
                                              const int2* __restrict__ er, const float* __restrict__ self_norm,
                                              const float* __restrict__ W0, const float* __restrict__ b0,
                                              _Float16* __restrict__ h0) {
    __shared__ float zs[64][4];
    const int tid = threadIdx.x;
    const int blk = blockIdx.x;
    {
        const int li = tid >> 2;         // local node 0..63
        const int slot = tid & 3;        // edge slot
        const int n = blk * 64 + li;
        const int beg = row_off[n], end = row_off[n + 1];
        float p0 = 0.f, p1 = 0.f, p2 = 0.f;
        for (int ei = beg + slot; ei < end; ei += 4) {
            int2 e = er[ei];
            float en = __int_as_float(e.y);
            const float* xs = x + 3 * (size_t)e.x;
            p0 = fmaf(xs[0], en, p0);
            p1 = fmaf(xs[1], en, p1);
            p2 = fmaf(xs[2], en, p2);
        }
        p0 += __shfl_xor(p0, 1); p1 += __shfl_xor(p1, 1); p2 += __shfl_xor(p2, 1);
        p0 += __shfl_xor(p0, 2); p1 += __shfl_xor(p1, 2); p2 += __shfl_xor(p2, 2);
        if (slot == 0) {
            const float sn = self_norm[n];
            const float* xn = x + 3 * (size_t)n;
            zs[li][0] = fmaf(xn[0], sn, p0);
            zs[li][1] = fmaf(xn[1], sn, p1);
            zs[li][2] = fmaf(xn[2], sn, p2);
        }
    }
    __syncthreads();
    // matvec: thread = col-pair jj, 16 nodes per wave-group
    const int jj = tid & 63;                  // col pair 0..63
    const int g = tid >> 6;                   // node group 0..3
    const int j = jj * 2;
    const float w00 = W0[j], w01 = W0[j + 1];
    const float w10 = W0[128 + j], w11 = W0[128 + j + 1];
    const float w20 = W0[256 + j], w21 = W0[256 + j + 1];
    const float bb0 = b0[j], bb1 = b0[j + 1];
#pragma unroll 4
    for (int i = 0; i < 16; ++i) {
        const int li = g * 16 + i;
        const float z0 = zs[li][0], z1 = zs[li][1], z2 = zs[li][2];
        float o0 = bb0 + z0 * w00 + z1 * w10 + z2 * w20;
        float o1 = bb1 + z0 * w01 + z1 * w11 + z2 * w21;
        f16x2v o;
        o[0] = (_Float16)fmaxf(o0, 0.f);
        o[1] = (_Float16)fmaxf(o1, 0.f);
        *(f16x2v*)(h0 + (size_t)(blk * 64 + li) * HID + j) = o;
    }
}

// ---------------- fused: aggregation (lane-per-node, wave-per-feature-slice) + GEMM1 MFMA -> h1 ----
// 64 nodes/block. Wave w owns cols [w*32, w*32+32); lane l owns node l's edge loop (32 f32 acc).
__global__ __launch_bounds__(256) void k_agg_mm(const _Float16* __restrict__ h0, const int* __restrict__ row_off,
                                                const int2* __restrict__ er, const float* __restrict__ self_norm,
                                                const _Float16* __restrict__ W1p, const float* __restrict__ b1,
                                                _Float16* __restrict__ h1) {
    __shared__ _Float16 As[64 * 136];  // rows padded to 136 f16 (272 B)
    const int tid = threadIdx.x;
    const int w = tid >> 6, lane = tid & 63;
    const int blk = blockIdx.x;

    // phase 1: per-lane gather-accumulate over own node's edges (cols w*32 + 0..31)
    {
        const int node = blk * 64 + lane;
        const int beg = row_off[node], end = row_off[node + 1];
        const _Float16* __restrict__ hcol = h0 + w * 32;
        f32x4 acc[8];
#pragma unroll
        for (int k = 0; k < 8; ++k) acc[k] = (f32x4){0.f, 0.f, 0.f, 0.f};
        // self term as first "edge"
        {
            const float sn = self_norm[node];
            const f16x8* rp = (const f16x8*)(hcol + (size_t)node * HID);
#pragma unroll
            for (int v4 = 0; v4 < 4; ++v4) {
                f16x8 v = rp[v4];
#pragma unroll
                for (int k = 0; k < 8; ++k) acc[v4 * 2 + (k >> 2)][k & 3] = fmaf((float)v[k], sn, acc[v4 * 2 + (k >> 2)][k & 3]);
            }
        }
        for (int ei = beg; ei < end; ++ei) {
            int2 e = er[ei];
            float en = __int_as_float(e.y);
            const f16x8* rp = (const f16x8*)(hcol + (size_t)e.x * HID);
            f16x8 v0 = rp[0], v1 = rp[1], v2 = rp[2], v3 = rp[3];
#pragma unroll
            for (int k = 0; k < 8; ++k) acc[0 + (k >> 2)][k & 3] = fmaf((float)v0[k], en, acc[0 + (k >> 2)][k & 3]);
#pragma unroll
            for (int k = 0; k < 8; ++k) acc[2 + (k >> 2)][k & 3] = fmaf((float)v1[k], en, acc[2 + (k >> 2)][k & 3]);
#pragma unroll
            for (int k = 0; k < 8; ++k) acc[4 + (k >> 2)][k & 3] = fmaf((float)v2[k], en, acc[4 + (k >> 2)][k & 3]);
#pragma unroll
            for (int k = 0; k < 8; ++k) acc[6 + (k >> 2)][k & 3] = fmaf((float)v3[k], en, acc[6 + (k >> 2)][k & 3]);
        }
        _Float16* dst = &As[lane * 136 + w * 32];
#pragma unroll
        for (int v4 = 0; v4 < 4; ++v4) {
            f16x8 o;
#pragma unroll
            for (int k = 0; k < 8; ++k) o[k] = (_Float16)acc[v4 * 2 + (k >> 2)][k & 3];
            *(f16x8*)(dst + v4 * 8) = o;
        }
    }
    __syncthreads();

    // phase 2: MFMA 16x128x128; wave w owns m-tile rows w*16..w*16+15
    const int q = lane >> 4, c = lane & 15;
    f16x8 afr[4];
#pragma unroll
    for (int kk = 0; kk < 4; ++kk) afr[kk] = *(const f16x8*)(&As[(w * 16 + c) * 136 + kk * 32 + q * 8]);
    const f16x8* __restrict__ Bv = (const f16x8*)W1p;
    _Float16* Cst = &As[w * 2176];  // reuse own As region for C staging ([16][128] f16)
#pragma unroll
    for (int j = 0; j < 8; ++j) {
        f32x4 cc = {0.f, 0.f, 0.f, 0.f};
#pragma unroll
        for (int kk = 0; kk < 4; ++kk)
            cc = __builtin_amdgcn_mfma_f32_16x16x32_f16(afr[kk], Bv[(j * 4 + kk) * 64 + lane], cc, 0, 0, 0);
        const float bi = b1[j * 16 + c];
#pragma unroll
        for (int r = 0; r < 4; ++r) Cst[(q * 4 + r) * 128 + j * 16 + c] = (_Float16)fmaxf(cc[r] + bi, 0.f);
    }
    // phase 3: coalesced store of own 16 rows
#pragma unroll
    for (int it = 0; it < 4; ++it) {
        int idx = it * 64 + lane;
        *(f16x8*)(h1 + (size_t)(blk * 64 + w * 16) * 128 + idx * 8) = *(const f16x8*)(&As[w * 2176 + idx * 8]);
    }
}

// ---------------- weight prep: GRU transposes (f32) + MFMA fragment packs (f16) ----------------
__global__ __launch_bounds__(256) void k_prep(const float* __restrict__ Wih, const float* __restrict__ Whh,
                                              const float* __restrict__ W1, const float* __restrict__ Wm,
                                              float* __restrict__ WihT, float* __restrict__ WhhT,
                                              _Float16* __restrict__ W1p, _Float16* __restrict__ Wmp) {
    int i = blockIdx.x * 256 + threadIdx.x;  // 0..49151
    {
        int o = i >> 7, k = i & 127;
        WihT[k * 384 + o] = Wih[i];
        WhhT[k * 384 + o] = Whh[i];
    }
    if (i < 16384) {
        int f = i >> 9;          // frag id 0..31
        int j = f >> 2, kk = f & 3;
        int lane = (i >> 3) & 63;
        int e = i & 7;
        int q = lane >> 4, p = lane & 15;
        int k = kk * 32 + q * 8 + e, n = j * 16 + p;
        W1p[i] = (_Float16)W1[k * 128 + n];
        Wmp[i] = (_Float16)Wm[k * 128 + n];
    }
}

// ---------------- fused: GEMM2 (f16 MFMA) + relu + frame mean + gi precompute ----------------
__global__ __launch_bounds__(256) void k_mm_pool(const _Float16* __restrict__ h1, const _Float16* __restrict__ Wmp,
                                                 const float* __restrict__ bm, const float* __restrict__ WihT,
                                                 const float* __restrict__ bih, float* __restrict__ GI) {
    __shared__ _Float16 As[80 * 136];
    __shared__ float colpart[4 * 128];
    __shared__ float fr[128];
    const int tid = threadIdx.x;
    const int w = tid >> 6, lane = tid & 63;
    const int q = lane >> 4, c = lane & 15;
    const int bt = blockIdx.x;

    const f16x8* __restrict__ srcv = (const f16x8*)(h1 + (size_t)bt * NPF * HID);
    for (int idx = tid; idx < 80 * 17; idx += 256) {
        int row = idx / 17, ch = idx % 17;
        f16x8 v;
        if (row < NPF && ch < 16) {
            v = srcv[row * 16 + ch];
        } else {
#pragma unroll
            for (int k = 0; k < 8; ++k) v[k] = (_Float16)0.f;
        }
        *(f16x8*)(&As[row * 136 + ch * 8]) = v;
    }
    __syncthreads();

    const f16x8* __restrict__ Bv = (const f16x8*)Wmp;
    const int npass = (w == 0) ? 2 : 1;
    for (int pass = 0; pass < npass; ++pass) {
        const int mt = pass ? 4 : w;
        f16x8 afr[4];
#pragma unroll
        for (int kk = 0; kk < 4; ++kk) afr[kk] = *(const f16x8*)(&As[(mt * 16 + c) * 136 + kk * 32 + q * 8]);
#pragma unroll
        for (int j = 0; j < 8; ++j) {
            f32x4 cc = {0.f, 0.f, 0.f, 0.f};
#pragma unroll
            for (int kk = 0; kk < 4; ++kk)
                cc = __builtin_amdgcn_mfma_f32_16x16x32_f16(afr[kk], Bv[(j * 4 + kk) * 64 + lane], cc, 0, 0, 0);
            const float bi = bm[j * 16 + c];
            float s = 0.f;
#pragma unroll
            for (int r = 0; r < 4; ++r) {
                int m = mt * 16 + q * 4 + r;
                float v = fmaxf(cc[r] + bi, 0.f);
                s += (m < NPF) ? v : 0.f;
            }
            s += __shfl_xor(s, 16);
            s += __shfl_xor(s, 32);
            if (lane < 16) {
                float* dst = &colpart[w * 128 + j * 16 + c];
                *dst = (pass == 0) ? s : (*dst + s);
            }
        }
    }
    __syncthreads();
    if (tid < 128)
        fr[tid] = (colpart[tid] + colpart[128 + tid] + colpart[256 + tid] + colpart[384 + tid]) * (1.0f / NPF);
    __syncthreads();
    if (tid < 128) {
#pragma unroll
        for (int p = 0; p < 3; ++p) {
            int o = tid + p * 128;
            float a = bih[o];
#pragma unroll 8
            for (int k = 0; k < 128; ++k) a = fmaf(fr[k], WihT[k * 384 + o], a);
            GI[(size_t)bt * 384 + o] = a;
        }
    }
}

// ---------------- GRU recurrence: one block per batch, W_hh^T rows in fp32 registers ----------------
__global__ __launch_bounds__(384) void k_gru(const float* __restrict__ GI, const float* __restrict__ WhhT,
                                             const float* __restrict__ bhh, float* __restrict__ hT) {
    __shared__ float hc[128];
    __shared__ float ghs[384];
    const int tid = threadIdx.x;
    const int b = blockIdx.x;
    float4 w[32];
#pragma unroll
    for (int k4 = 0; k4 < 32; ++k4) {
        w[k4].x = WhhT[(4 * k4 + 0) * 384 + tid];
        w[k4].y = WhhT[(4 * k4 + 1) * 384 + tid];
        w[k4].z = WhhT[(4 * k4 + 2) * 384 + tid];
        w[k4].w = WhhT[(4 * k4 + 3) * 384 + tid];
    }
    if (tid < 128) hc[tid] = 0.f;
    const float bh = bhh[tid];
    __syncthreads();
    for (int t = 0; t < T_SZ; ++t) {
        float a0 = bh, a1 = 0.f, a2 = 0.f, a3 = 0.f;
        const float4* h4 = (const float4*)hc;
#pragma unroll
        for (int k4 = 0; k4 < 32; ++k4) {
            float4 hv = h4[k4];
            a0 = fmaf(w[k4].x, hv.x, a0);
            a1 = fmaf(w[k4].y, hv.y, a1);
            a2 = fmaf(w[k4].z, hv.z, a2);
            a3 = fmaf(w[k4].w, hv.w, a3);
        }
        ghs[tid] = (a0 + a1) + (a2 + a3);
        __syncthreads();
        if (tid < 128) {
            const float* gi = GI + (size_t)(b * T_SZ + t) * 384;
            float ir = gi[tid], iz = gi[128 + tid], inn = gi[256 + tid];
            float hrv = ghs[tid], hz = ghs[128 + tid], hn = ghs[256 + tid];
            float r = 1.f / (1.f + expf(-(ir + hrv)));
            float z = 1.f / (1.f + expf(-(iz + hz)));
            float nn = tanhf(inn + r * hn);
            float hnew = (1.f - z) * nn + z * hc[tid];
            hc[tid] = hnew;
        }
        __syncthreads();
    }
    if (tid < 128) hT[b * 128 + tid] = hc[tid];
}

// ---------------- classifier head (384 threads: phase 2 needs 320) ----------------
__global__ __launch_bounds__(384) void k_cls(const float* __restrict__ hT, const float* __restrict__ Wc1,
                                             const float* __restrict__ bc1, const float* __restrict__ Wc2,
                                             const float* __restrict__ bc2, float* __restrict__ out) {
    __shared__ float hid[32 * 64];
    int tid = threadIdx.x;
    for (int idx = tid; idx < 2048; idx += 384) {
        int b = idx >> 6, j = idx & 63;
        float a = bc1[j];
#pragma unroll 8
        for (int k = 0; k < 128; ++k) a = fmaf(hT[b * 128 + k], Wc1[k * 64 + j], a);
        hid[idx] = fmaxf(a, 0.f);
    }
    __syncthreads();
    if (tid < 320) {
        int b = tid / 10, c = tid % 10;
        float a = bc2[c];
#pragma unroll 8
        for (int k = 0; k < 64; ++k) a = fmaf(hid[b * 64 + k], Wc2[k * 10 + c], a);
        out[tid] = a;
    }
}

extern "C" void kernel_launch(void* const* d_in, const int* in_sizes, int n_in, void* d_out, int out_size, void* d_ws,
                              size_t ws_size, hipStream_t stream) {
    const float* x = (const float*)d_in[0];
    const int* ei = (const int*)d_in[1];
    const int* e_src = ei;
    const int* e_dst = ei + E_TOT;
    const float* W0 = (const float*)d_in[2];
    const float* b0 = (const float*)d_in[3];
    const float* W1 = (const float*)d_in[4];
    const float* b1 = (const float*)d_in[5];
    const float* Wm = (const float*)d_in[6];
    const float* bm = (const float*)d_in[7];
    const float* Wih = (const float*)d_in[8];
    const float* Whh = (const float*)d_in[9];
    const float* bih = (const float*)d_in[10];
    const float* bhh = (const float*)d_in[11];
    const float* Wc1 = (const float*)d_in[12];
    const float* bc1 = (const float*)d_in[13];
    const float* Wc2 = (const float*)d_in[14];
    const float* bc2 = (const float*)d_in[15];
    float* out = (float*)d_out;

    char* base = (char*)d_ws;
    size_t off = 0;
    auto alloc = [&](size_t bytes) {
        size_t o = off;
        off = (off + bytes + 255) & ~(size_t)255;
        return o;
    };
    size_t o_cnt = alloc((size_t)NN_TOT * 4);
    size_t o_cursor = alloc((size_t)NN_TOT * 4);  // contiguous with cnt for one memset
    size_t o_rowoff = alloc((size_t)(NN_TOT + 1) * 4);
    size_t o_bsums = alloc(256 * 4);
    size_t o_disqrt = alloc((size_t)NN_TOT * 4);
    size_t o_snorm = alloc((size_t)NN_TOT * 4);
    size_t o_er = alloc((size_t)E_TOT * 8);
    size_t o_gi = alloc((size_t)B_SZ * T_SZ * 384 * 4);
    size_t o_wiht = alloc((size_t)128 * 384 * 4);
    size_t o_whht = alloc((size_t)128 * 384 * 4);
    size_t o_w1p = alloc((size_t)128 * 128 * 2);
    size_t o_wmp = alloc((size_t)128 * 128 * 2);
    size_t o_ht = alloc((size_t)B_SZ * 128 * 4);
    size_t o_h0 = alloc((size_t)NN_TOT * HID * 2);
    size_t o_h1 = alloc((size_t)NN_TOT * HID * 2);
    if (off > ws_size) return;  // workspace too small -> visible validation failure

    int* cnt = (int*)(base + o_cnt);
    int* cursor = (int*)(base + o_cursor);
    int* row_off = (int*)(base + o_rowoff);
    int* bsums = (int*)(base + o_bsums);
    float* d_isqrt = (float*)(base + o_disqrt);
    float* self_norm = (float*)(base + o_snorm);
    int2* er = (int2*)(base + o_er);
    float* GI = (float*)(base + o_gi);
    float* WihT = (float*)(base + o_wiht);
    float* WhhT = (float*)(base + o_whht);
    _Float16* W1p = (_Float16*)(base + o_w1p);
    _Float16* Wmp = (_Float16*)(base + o_wmp);
    float* hT = (float*)(base + o_ht);
    _Float16* h0 = (_Float16*)(base + o_h0);
    _Float16* h1 = (_Float16*)(base + o_h1);

    hipMemsetAsync(base + o_cnt, 0, (size_t)2 * NN_TOT * 4, stream);  // cnt + cursor

    k_deg<<<E_TOT / 256, 256, 0, stream>>>(e_dst, cnt);
    k_dinv<<<NN_TOT / 256, 256, 0, stream>>>(cnt, d_isqrt, self_norm);
    k_scan1<<<NN_TOT / 1024, 256, 0, stream>>>(cnt, row_off, bsums);
    k_scan2<<<1, 256, 0, stream>>>(bsums, NN_TOT / 1024);
    k_scan3<<<NN_TOT / 256, 256, 0, stream>>>(row_off, bsums);
    k_scatter<<<E_TOT / 256, 256, 0, stream>>>(e_src, e_dst, d_isqrt, row_off, cursor, er);
    k_prep<<<(384 * 128) / 256, 256, 0, stream>>>(Wih, Whh, W1, Wm, WihT, WhhT, W1p, Wmp);
    k_gcn0<<<NN_TOT / 64, 256, 0, stream>>>(x, row_off, er, self_norm, W0, b0, h0);
    k_agg_mm<<<NN_TOT / 64, 256, 0, stream>>>(h0, row_off, er, self_norm, W1p, b1, h1);
    k_mm_pool<<<B_SZ * T_SZ, 256, 0, stream>>>(h1, Wmp, bm, WihT, bih, GI);
    k_gru<<<B_SZ, 384, 0, stream>>>(GI, WhhT, bhh, hT);
    k_cls<<<1, 384, 0, stream>>>(hT, Wc1, bc1, Wc2, bc2, out);
}

// Round 6
// 584.320 us; speedup vs baseline: 1.6930x; 1.0734x over previous
//
#include <hip/hip_runtime.h>

#define NN_TOT 208896      // 32*96*68 nodes
#define E_TOT  1671168     // NN_TOT*8 edges
#define B_SZ   32
#define T_SZ   96
#define NPF    68          // nodes per frame
#define HID    128

typedef _Float16 f16x8 __attribute__((ext_vector_type(8)));
typedef _Float16 f16x2v __attribute__((ext_vector_type(2)));
typedef float f32x4 __attribute__((ext_vector_type(4)));

// ---------------- degree count ----------------
__global__ __launch_bounds__(256) void k_deg(const int* __restrict__ dst, int* __restrict__ cnt) {
    int e = blockIdx.x * 256 + threadIdx.x;
    atomicAdd(&cnt[dst[e]], 1);
}

// ---------------- 1/sqrt(deg), 1/deg ----------------
__global__ __launch_bounds__(256) void k_dinv(const int* __restrict__ cnt, float* __restrict__ d_isqrt,
                                              float* __restrict__ self_norm) {
    int i = blockIdx.x * 256 + threadIdx.x;
    float deg = (float)(1 + cnt[i]);
    float is = 1.0f / sqrtf(deg);
    d_isqrt[i] = is;
    self_norm[i] = is * is;
}

// ---------------- exclusive scan (3 kernels, 1024 elems/block) ----------------
__global__ __launch_bounds__(256) void k_scan1(const int* __restrict__ cnt, int* __restrict__ row_off,
                                               int* __restrict__ bsums) {
    __shared__ int ts[256];
    int tid = threadIdx.x;
    int base = blockIdx.x * 1024 + tid * 4;
    int v0 = cnt[base], v1 = cnt[base + 1], v2 = cnt[base + 2], v3 = cnt[base + 3];
    int s = v0 + v1 + v2 + v3;
    ts[tid] = s;
    __syncthreads();
    int inc = s;
    for (int off = 1; off < 256; off <<= 1) {
        int add = (tid >= off) ? ts[tid - off] : 0;
        __syncthreads();
        inc += add;
        ts[tid] = inc;
        __syncthreads();
    }
    int excl = inc - s;
    row_off[base] = excl;
    row_off[base + 1] = excl + v0;
    row_off[base + 2] = excl + v0 + v1;
    row_off[base + 3] = excl + v0 + v1 + v2;
    if (tid == 255) bsums[blockIdx.x] = inc;
}

__global__ __launch_bounds__(256) void k_scan2(int* __restrict__ bsums, int nb) {
    __shared__ int ts[256];
    int tid = threadIdx.x;
    int v = (tid < nb) ? bsums[tid] : 0;
    ts[tid] = v;
    __syncthreads();
    int inc = v;
    for (int off = 1; off < 256; off <<= 1) {
        int add = (tid >= off) ? ts[tid - off] : 0;
        __syncthreads();
        inc += add;
        ts[tid] = inc;
        __syncthreads();
    }
    if (tid < nb) bsums[tid] = inc - v;
}

__global__ __launch_bounds__(256) void k_scan3(int* __restrict__ row_off, const int* __restrict__ bsums) {
    int i = blockIdx.x * 256 + threadIdx.x;
    row_off[i] += bsums[i >> 10];
    if (i == 0) row_off[NN_TOT] = E_TOT;
}

// ---------------- CSR scatter: packed (src, norm) int2 ----------------
__global__ __launch_bounds__(256) void k_scatter(const int* __restrict__ src, const int* __restrict__ dst,
                                                 const float* __restrict__ d_isqrt, const int* __restrict__ row_off,
                                                 int* __restrict__ cursor, int2* __restrict__ er) {
    int e = blockIdx.x * 256 + threadIdx.x;
    int s = src[e], d = dst[e];
    float en = d_isqrt[s] * d_isqrt[d];
    int p = atomicAdd(&cursor[d], 1);
    int idx = row_off[d] + p;
    er[idx] = make_int2(s, __float_as_int(en));
}

// ---------------- GCN layer 0: 64 nodes/block, 4 edge-slots/node, then block matvec ----------------
__global__ __launch_bounds__(256) void k_gcn0(const float* __restrict__ x, const int* __restrict__ row_off,
                                              const int2* __restrict__ er, const float* __restrict__ self_norm,
                                              const float* __restrict__ W0, const float* __restrict__ b0,
                                              _Float16* __restrict__ h0) {
    __shared__ float zs[64][4];
    const int tid = threadIdx.x;
    const int blk = blockIdx.x;
    {
        const int li = tid >> 2;         // local node 0..63
        const int slot = tid & 3;        // edge slot
        const int n = blk * 64 + li;
        const int beg = row_off[n], end = row_off[n + 1];
        float p0 = 0.f, p1 = 0.f, p2 = 0.f;
        for (int ei = beg + slot; ei < end; ei += 4) {
            int2 e = er[ei];
            float en = __int_as_float(e.y);
            const float* xs = x + 3 * (size_t)e.x;
            p0 = fmaf(xs[0], en, p0);
            p1 = fmaf(xs[1], en, p1);
            p2 = fmaf(xs[2], en, p2);
        }
        p0 += __shfl_xor(p0, 1); p1 += __shfl_xor(p1, 1); p2 += __shfl_xor(p2, 1);
        p0 += __shfl_xor(p0, 2); p1 += __shfl_xor(p1, 2); p2 += __shfl_xor(p2, 2);
        if (slot == 0) {
            const float sn = self_norm[n];
            const float* xn = x + 3 * (size_t)n;
            zs[li][0] = fmaf(xn[0], sn, p0);
            zs[li][1] = fmaf(xn[1], sn, p1);
            zs[li][2] = fmaf(xn[2], sn, p2);
        }
    }
    __syncthreads();
    // matvec: thread = col-pair jj, 16 nodes per wave-group
    const int jj = tid & 63;                  // col pair 0..63
    const int g = tid >> 6;                   // node group 0..3
    const int j = jj * 2;
    const float w00 = W0[j], w01 = W0[j + 1];
    const float w10 = W0[128 + j], w11 = W0[128 + j + 1];
    const float w20 = W0[256 + j], w21 = W0[256 + j + 1];
    const float bb0 = b0[j], bb1 = b0[j + 1];
#pragma unroll 4
    for (int i = 0; i < 16; ++i) {
        const int li = g * 16 + i;
        const float z0 = zs[li][0], z1 = zs[li][1], z2 = zs[li][2];
        float o0 = bb0 + z0 * w00 + z1 * w10 + z2 * w20;
        float o1 = bb1 + z0 * w01 + z1 * w11 + z2 * w21;
        f16x2v o;
        o[0] = (_Float16)fmaxf(o0, 0.f);
        o[1] = (_Float16)fmaxf(o1, 0.f);
        *(f16x2v*)(h0 + (size_t)(blk * 64 + li) * HID + j) = o;
    }
}

// ---------------- fused: aggregation (lane-per-node, wave-per-feature-slice) + GEMM1 MFMA -> h1 ----
__global__ __launch_bounds__(256) void k_agg_mm(const _Float16* __restrict__ h0, const int* __restrict__ row_off,
                                                const int2* __restrict__ er, const float* __restrict__ self_norm,
                                                const _Float16* __restrict__ W1p, const float* __restrict__ b1,
                                                _Float16* __restrict__ h1) {
    __shared__ __align__(16) _Float16 As[64 * 136];  // rows padded to 136 f16 (272 B)
    const int tid = threadIdx.x;
    const int w = tid >> 6, lane = tid & 63;
    const int blk = blockIdx.x;

    // phase 1: per-lane gather-accumulate over own node's edges (cols w*32 + 0..31)
    {
        const int node = blk * 64 + lane;
        const int beg = row_off[node], end = row_off[node + 1];
        const _Float16* __restrict__ hcol = h0 + w * 32;
        f32x4 acc[8];
#pragma unroll
        for (int k = 0; k < 8; ++k) acc[k] = (f32x4){0.f, 0.f, 0.f, 0.f};
        {
            const float sn = self_norm[node];
            const f16x8* rp = (const f16x8*)(hcol + (size_t)node * HID);
#pragma unroll
            for (int v4 = 0; v4 < 4; ++v4) {
                f16x8 v = rp[v4];
#pragma unroll
                for (int k = 0; k < 8; ++k) acc[v4 * 2 + (k >> 2)][k & 3] = fmaf((float)v[k], sn, acc[v4 * 2 + (k >> 2)][k & 3]);
            }
        }
        for (int ei = beg; ei < end; ++ei) {
            int2 e = er[ei];
            float en = __int_as_float(e.y);
            const f16x8* rp = (const f16x8*)(hcol + (size_t)e.x * HID);
            f16x8 v0 = rp[0], v1 = rp[1], v2 = rp[2], v3 = rp[3];
#pragma unroll
            for (int k = 0; k < 8; ++k) acc[0 + (k >> 2)][k & 3] = fmaf((float)v0[k], en, acc[0 + (k >> 2)][k & 3]);
#pragma unroll
            for (int k = 0; k < 8; ++k) acc[2 + (k >> 2)][k & 3] = fmaf((float)v1[k], en, acc[2 + (k >> 2)][k & 3]);
#pragma unroll
            for (int k = 0; k < 8; ++k) acc[4 + (k >> 2)][k & 3] = fmaf((float)v2[k], en, acc[4 + (k >> 2)][k & 3]);
#pragma unroll
            for (int k = 0; k < 8; ++k) acc[6 + (k >> 2)][k & 3] = fmaf((float)v3[k], en, acc[6 + (k >> 2)][k & 3]);
        }
        _Float16* dst = &As[lane * 136 + w * 32];
#pragma unroll
        for (int v4 = 0; v4 < 4; ++v4) {
            f16x8 o;
#pragma unroll
            for (int k = 0; k < 8; ++k) o[k] = (_Float16)acc[v4 * 2 + (k >> 2)][k & 3];
            *(f16x8*)(dst + v4 * 8) = o;
        }
    }
    __syncthreads();

    // phase 2: MFMA 16x128x128; wave w owns m-tile rows w*16..w*16+15
    const int q = lane >> 4, c = lane & 15;
    f16x8 afr[4];
#pragma unroll
    for (int kk = 0; kk < 4; ++kk) afr[kk] = *(const f16x8*)(&As[(w * 16 + c) * 136 + kk * 32 + q * 8]);
    const f16x8* __restrict__ Bv = (const f16x8*)W1p;
    _Float16* Cst = &As[w * 2176];
#pragma unroll
    for (int j = 0; j < 8; ++j) {
        f32x4 cc = {0.f, 0.f, 0.f, 0.f};
#pragma unroll
        for (int kk = 0; kk < 4; ++kk)
            cc = __builtin_amdgcn_mfma_f32_16x16x32_f16(afr[kk], Bv[(j * 4 + kk) * 64 + lane], cc, 0, 0, 0);
        const float bi = b1[j * 16 + c];
#pragma unroll
        for (int r = 0; r < 4; ++r) Cst[(q * 4 + r) * 128 + j * 16 + c] = (_Float16)fmaxf(cc[r] + bi, 0.f);
    }
#pragma unroll
    for (int it = 0; it < 4; ++it) {
        int idx = it * 64 + lane;
        *(f16x8*)(h1 + (size_t)(blk * 64 + w * 16) * 128 + idx * 8) = *(const f16x8*)(&As[w * 2176 + idx * 8]);
    }
}

// ---------------- weight prep: WihT (f32) + MFMA fragment packs (f16) ----------------
__global__ __launch_bounds__(256) void k_prep(const float* __restrict__ Wih, const float* __restrict__ W1,
                                              const float* __restrict__ Wm, float* __restrict__ WihT,
                                              _Float16* __restrict__ W1p, _Float16* __restrict__ Wmp) {
    int i = blockIdx.x * 256 + threadIdx.x;  // 0..49151
    {
        int o = i >> 7, k = i & 127;
        WihT[k * 384 + o] = Wih[i];
    }
    if (i < 16384) {
        int f = i >> 9;          // frag id 0..31
        int j = f >> 2, kk = f & 3;
        int lane = (i >> 3) & 63;
        int e = i & 7;
        int q = lane >> 4, p = lane & 15;
        int k = kk * 32 + q * 8 + e, n = j * 16 + p;
        W1p[i] = (_Float16)W1[k * 128 + n];
        Wmp[i] = (_Float16)Wm[k * 128 + n];
    }
}

// ---------------- fused: GEMM2 (f16 MFMA) + relu + frame mean + gi precompute (time-major out) ----
__global__ __launch_bounds__(256) void k_mm_pool(const _Float16* __restrict__ h1, const _Float16* __restrict__ Wmp,
                                                 const float* __restrict__ bm, const float* __restrict__ WihT,
                                                 const float* __restrict__ bih, float* __restrict__ GIt) {
    __shared__ __align__(16) _Float16 As[80 * 136];
    __shared__ float colpart[4 * 128];
    __shared__ float fr[128];
    const int tid = threadIdx.x;
    const int w = tid >> 6, lane = tid & 63;
    const int q = lane >> 4, c = lane & 15;
    const int bt = blockIdx.x;
    const int bb = bt / T_SZ, tt = bt % T_SZ;

    const f16x8* __restrict__ srcv = (const f16x8*)(h1 + (size_t)bt * NPF * HID);
    for (int idx = tid; idx < 80 * 17; idx += 256) {
        int row = idx / 17, ch = idx % 17;
        f16x8 v;
        if (row < NPF && ch < 16) {
            v = srcv[row * 16 + ch];
        } else {
#pragma unroll
            for (int k = 0; k < 8; ++k) v[k] = (_Float16)0.f;
        }
        *(f16x8*)(&As[row * 136 + ch * 8]) = v;
    }
    __syncthreads();

    const f16x8* __restrict__ Bv = (const f16x8*)Wmp;
    const int npass = (w == 0) ? 2 : 1;
    for (int pass = 0; pass < npass; ++pass) {
        const int mt = pass ? 4 : w;
        f16x8 afr[4];
#pragma unroll
        for (int kk = 0; kk < 4; ++kk) afr[kk] = *(const f16x8*)(&As[(mt * 16 + c) * 136 + kk * 32 + q * 8]);
#pragma unroll
        for (int j = 0; j < 8; ++j) {
            f32x4 cc = {0.f, 0.f, 0.f, 0.f};
#pragma unroll
            for (int kk = 0; kk < 4; ++kk)
                cc = __builtin_amdgcn_mfma_f32_16x16x32_f16(afr[kk], Bv[(j * 4 + kk) * 64 + lane], cc, 0, 0, 0);
            const float bi = bm[j * 16 + c];
            float s = 0.f;
#pragma unroll
            for (int r = 0; r < 4; ++r) {
                int m = mt * 16 + q * 4 + r;
                float v = fmaxf(cc[r] + bi, 0.f);
                s += (m < NPF) ? v : 0.f;
            }
            s += __shfl_xor(s, 16);
            s += __shfl_xor(s, 32);
            if (lane < 16) {
                float* dst = &colpart[w * 128 + j * 16 + c];
                *dst = (pass == 0) ? s : (*dst + s);
            }
        }
    }
    __syncthreads();
    if (tid < 128)
        fr[tid] = (colpart[tid] + colpart[128 + tid] + colpart[256 + tid] + colpart[384 + tid]) * (1.0f / NPF);
    __syncthreads();
    if (tid < 128) {
#pragma unroll
        for (int p = 0; p < 3; ++p) {
            int o = tid + p * 128;
            float a = bih[o];
#pragma unroll 8
            for (int k = 0; k < 128; ++k) a = fmaf(fr[k], WihT[k * 384 + o], a);
            GIt[((size_t)tt * B_SZ + bb) * 384 + o] = a;  // time-major for the GRU
        }
    }
}

// ---------------- GRU recurrence: MFMA-batched (16 batches = M-tile), 2 blocks x 8 waves ----------
// Wave w owns n-tiles {w, 8+w, 16+w} = gates r/z/n of outputs 16w..16w+15 -> gate math is lane-local.
__global__ __launch_bounds__(512) void k_gru(const float* __restrict__ GIt, const float* __restrict__ Whh,
                                             const float* __restrict__ bhh, float* __restrict__ hT) {
    __shared__ __align__(16) _Float16 hbuf[16 * 144];  // [batch][feat], row stride 144 (4-way max on frag reads)
    const int tid = threadIdx.x;
    const int w = tid >> 6, lane = tid & 63;
    const int q = lane >> 4, c = lane & 15;
    const int B = blockIdx.x;  // batches 16B..16B+15

    // B-frags from global Whh (row o = output, col k = feature), cvt to f16: 48 VGPRs
    f16x8 bfr[3][4];
#pragma unroll
    for (int g = 0; g < 3; ++g) {
        const int o = g * 128 + 16 * w + c;
#pragma unroll
        for (int kk = 0; kk < 4; ++kk) {
            const float* p = Whh + (size_t)o * 128 + kk * 32 + q * 8;
            float4 u = *(const float4*)p, v = *(const float4*)(p + 4);
            f16x8 f;
            f[0] = (_Float16)u.x; f[1] = (_Float16)u.y; f[2] = (_Float16)u.z; f[3] = (_Float16)u.w;
            f[4] = (_Float16)v.x; f[5] = (_Float16)v.y; f[6] = (_Float16)v.z; f[7] = (_Float16)v.w;
            bfr[g][kk] = f;
        }
    }
    const float bh0 = bhh[16 * w + c], bh1 = bhh[128 + 16 * w + c], bh2 = bhh[256 + 16 * w + c];
    for (int i = tid; i < 16 * 144 / 2; i += 512) ((unsigned int*)hbuf)[i] = 0u;
    float h[4] = {0.f, 0.f, 0.f, 0.f};
    float gc[3][4];
#pragma unroll
    for (int r = 0; r < 4; ++r) {
        size_t row = (size_t)(B * 16 + q * 4 + r) * 384 + 16 * w + c;  // t = 0
#pragma unroll
        for (int g = 0; g < 3; ++g) gc[g][r] = GIt[row + g * 128];
    }
    __syncthreads();

    for (int t = 0; t < T_SZ; ++t) {
        f16x8 afr[4];
#pragma unroll
        for (int kk = 0; kk < 4; ++kk) afr[kk] = *(const f16x8*)(&hbuf[c * 144 + kk * 32 + q * 8]);
        __syncthreads();  // all frag reads done before anyone writes new h
        // prefetch next step's gi (L2-resident, hidden behind MFMA)
        float gn[3][4];
        const int tn = (t + 1 < T_SZ) ? t + 1 : T_SZ - 1;
#pragma unroll
        for (int r = 0; r < 4; ++r) {
            size_t row = ((size_t)tn * B_SZ + B * 16 + q * 4 + r) * 384 + 16 * w + c;
#pragma unroll
            for (int g = 0; g < 3; ++g) gn[g][r] = GIt[row + g * 128];
        }
        f32x4 cc[3];
#pragma unroll
        for (int g = 0; g < 3; ++g) {
            f32x4 a = {0.f, 0.f, 0.f, 0.f};
#pragma unroll
            for (int kk = 0; kk < 4; ++kk) a = __builtin_amdgcn_mfma_f32_16x16x32_f16(afr[kk], bfr[g][kk], a, 0, 0, 0);
            cc[g] = a;
        }
#pragma unroll
        for (int r = 0; r < 4; ++r) {
            float hr = cc[0][r] + bh0, hz = cc[1][r] + bh1, hn = cc[2][r] + bh2;
            float rg = 1.f / (1.f + __expf(-(gc[0][r] + hr)));
            float zg = 1.f / (1.f + __expf(-(gc[1][r] + hz)));
            float arg = gc[2][r] + rg * hn;
            float nn = 1.f - 2.f / (__expf(2.f * arg) + 1.f);
            h[r] = (1.f - zg) * nn + zg * h[r];
            hbuf[(q * 4 + r) * 144 + 16 * w + c] = (_Float16)h[r];
        }
#pragma unroll
        for (int r = 0; r < 4; ++r) {
            gc[0][r] = gn[0][r]; gc[1][r] = gn[1][r]; gc[2][r] = gn[2][r];
        }
        __syncthreads();  // new h visible
    }
#pragma unroll
    for (int r = 0; r < 4; ++r) hT[(size_t)(B * 16 + q * 4 + r) * 128 + 16 * w + c] = h[r];
}

// ---------------- classifier head (384 threads: phase 2 needs 320) ----------------
__global__ __launch_bounds__(384) void k_cls(const float* __restrict__ hT, const float* __restrict__ Wc1,
                                             const float* __restrict__ bc1, const float* __restrict__ Wc2,
                                             const float* __restrict__ bc2, float* __restrict__ out) {
    __shared__ float hid[32 * 64];
    int tid = threadIdx.x;
    for (int idx = tid; idx < 2048; idx += 384) {
        int b = idx >> 6, j = idx & 63;
        float a = bc1[j];
#pragma unroll 8
        for (int k = 0; k < 128; ++k) a = fmaf(hT[b * 128 + k], Wc1[k * 64 + j], a);
        hid[idx] = fmaxf(a, 0.f);
    }
    __syncthreads();
    if (tid < 320) {
        int b = tid / 10, c = tid % 10;
        float a = bc2[c];
#pragma unroll 8
        for (int k = 0; k < 64; ++k) a = fmaf(hid[b * 64 + k], Wc2[k * 10 + c], a);
        out[tid] = a;
    }
}

extern "C" void kernel_launch(void* const* d_in, const int* in_sizes, int n_in, void* d_out, int out_size, void* d_ws,
                              size_t ws_size, hipStream_t stream) {
    const float* x = (const float*)d_in[0];
    const int* ei = (const int*)d_in[1];
    const int* e_src = ei;
    const int* e_dst = ei + E_TOT;
    const float* W0 = (const float*)d_in[2];
    const float* b0 = (const float*)d_in[3];
    const float* W1 = (const float*)d_in[4];
    const float* b1 = (const float*)d_in[5];
    const float* Wm = (const float*)d_in[6];
    const float* bm = (const float*)d_in[7];
    const float* Wih = (const float*)d_in[8];
    const float* Whh = (const float*)d_in[9];
    const float* bih = (const float*)d_in[10];
    const float* bhh = (const float*)d_in[11];
    const float* Wc1 = (const float*)d_in[12];
    const float* bc1 = (const float*)d_in[13];
    const float* Wc2 = (const float*)d_in[14];
    const float* bc2 = (const float*)d_in[15];
    float* out = (float*)d_out;

    char* base = (char*)d_ws;
    size_t off = 0;
    auto alloc = [&](size_t bytes) {
        size_t o = off;
        off = (off + bytes + 255) & ~(size_t)255;
        return o;
    };
    size_t o_cnt = alloc((size_t)NN_TOT * 4);
    size_t o_cursor = alloc((size_t)NN_TOT * 4);  // contiguous with cnt for one memset
    size_t o_rowoff = alloc((size_t)(NN_TOT + 1) * 4);
    size_t o_bsums = alloc(256 * 4);
    size_t o_disqrt = alloc((size_t)NN_TOT * 4);
    size_t o_snorm = alloc((size_t)NN_TOT * 4);
    size_t o_er = alloc((size_t)E_TOT * 8);
    size_t o_gi = alloc((size_t)B_SZ * T_SZ * 384 * 4);
    size_t o_wiht = alloc((size_t)128 * 384 * 4);
    size_t o_w1p = alloc((size_t)128 * 128 * 2);
    size_t o_wmp = alloc((size_t)128 * 128 * 2);
    size_t o_ht = alloc((size_t)B_SZ * 128 * 4);
    size_t o_h0 = alloc((size_t)NN_TOT * HID * 2);
    size_t o_h1 = alloc((size_t)NN_TOT * HID * 2);
    if (off > ws_size) return;  // workspace too small -> visible validation failure

    int* cnt = (int*)(base + o_cnt);
    int* cursor = (int*)(base + o_cursor);
    int* row_off = (int*)(base + o_rowoff);
    int* bsums = (int*)(base + o_bsums);
    float* d_isqrt = (float*)(base + o_disqrt);
    float* self_norm = (float*)(base + o_snorm);
    int2* er = (int2*)(base + o_er);
    float* GIt = (float*)(base + o_gi);
    float* WihT = (float*)(base + o_wiht);
    _Float16* W1p = (_Float16*)(base + o_w1p);
    _Float16* Wmp = (_Float16*)(base + o_wmp);
    float* hT = (float*)(base + o_ht);
    _Float16* h0 = (_Float16*)(base + o_h0);
    _Float16* h1 = (_Float16*)(base + o_h1);

    hipMemsetAsync(base + o_cnt, 0, (size_t)2 * NN_TOT * 4, stream);  // cnt + cursor

    k_deg<<<E_TOT / 256, 256, 0, stream>>>(e_dst, cnt);
    k_dinv<<<NN_TOT / 256, 256, 0, stream>>>(cnt, d_isqrt, self_norm);
    k_scan1<<<NN_TOT / 1024, 256, 0, stream>>>(cnt, row_off, bsums);
    k_scan2<<<1, 256, 0, stream>>>(bsums, NN_TOT / 1024);
    k_scan3<<<NN_TOT / 256, 256, 0, stream>>>(row_off, bsums);
    k_scatter<<<E_TOT / 256, 256, 0, stream>>>(e_src, e_dst, d_isqrt, row_off, cursor, er);
    k_prep<<<(384 * 128) / 256, 256, 0, stream>>>(Wih, W1, Wm, WihT, W1p, Wmp);
    k_gcn0<<<NN_TOT / 64, 256, 0, stream>>>(x, row_off, er, self_norm, W0, b0, h0);
    k_agg_mm<<<NN_TOT / 64, 256, 0, stream>>>(h0, row_off, er, self_norm, W1p, b1, h1);
    k_mm_pool<<<B_SZ * T_SZ, 256, 0, stream>>>(h1, Wmp, bm, WihT, bih, GIt);
    k_gru<<<2, 512, 0, stream>>>(GIt, Whh, bhh, hT);
    k_cls<<<1, 384, 0, stream>>>(hT, Wc1, bc1, Wc2, bc2, out);
}

// Round 7
// 577.387 us; speedup vs baseline: 1.7134x; 1.0120x over previous
//
#include <hip/hip_runtime.h>

#define NN_TOT 208896      // 32*96*68 nodes
#define E_TOT  1671168     // NN_TOT*8 edges
#define B_SZ   32
#define T_SZ   96
#define NPF    68          // nodes per frame
#define HID    128

typedef _Float16 f16x8 __attribute__((ext_vector_type(8)));
typedef _Float16 f16x2v __attribute__((ext_vector_type(2)));
typedef float f32x4 __attribute__((ext_vector_type(4)));

// ---------------- degree count (int4, 4 atomics/thread) ----------------
__global__ __launch_bounds__(256) void k_deg(const int4* __restrict__ dst4, int* __restrict__ cnt) {
    int e = blockIdx.x * 256 + threadIdx.x;
    int4 d = dst4[e];
    atomicAdd(&cnt[d.x], 1);
    atomicAdd(&cnt[d.y], 1);
    atomicAdd(&cnt[d.z], 1);
    atomicAdd(&cnt[d.w], 1);
}

// ---------------- scan part 1 (+ fused deg->norm) ----------------
__global__ __launch_bounds__(256) void k_scan1(const int* __restrict__ cnt, int* __restrict__ row_off,
                                               int* __restrict__ bsums, float* __restrict__ d_isqrt,
                                               float* __restrict__ self_norm) {
    __shared__ int ts[256];
    int tid = threadIdx.x;
    int base = blockIdx.x * 1024 + tid * 4;
    int v0 = cnt[base], v1 = cnt[base + 1], v2 = cnt[base + 2], v3 = cnt[base + 3];
#pragma unroll
    for (int u = 0; u < 4; ++u) {
        int vv = (u == 0) ? v0 : (u == 1) ? v1 : (u == 2) ? v2 : v3;
        float deg = (float)(1 + vv);
        float is = 1.0f / sqrtf(deg);
        d_isqrt[base + u] = is;
        self_norm[base + u] = is * is;
    }
    int s = v0 + v1 + v2 + v3;
    ts[tid] = s;
    __syncthreads();
    int inc = s;
    for (int off = 1; off < 256; off <<= 1) {
        int add = (tid >= off) ? ts[tid - off] : 0;
        __syncthreads();
        inc += add;
        ts[tid] = inc;
        __syncthreads();
    }
    int excl = inc - s;
    row_off[base] = excl;
    row_off[base + 1] = excl + v0;
    row_off[base + 2] = excl + v0 + v1;
    row_off[base + 3] = excl + v0 + v1 + v2;
    if (tid == 255) bsums[blockIdx.x] = inc;
}

__global__ __launch_bounds__(256) void k_scan2(int* __restrict__ bsums, int nb) {
    __shared__ int ts[256];
    int tid = threadIdx.x;
    int v = (tid < nb) ? bsums[tid] : 0;
    ts[tid] = v;
    __syncthreads();
    int inc = v;
    for (int off = 1; off < 256; off <<= 1) {
        int add = (tid >= off) ? ts[tid - off] : 0;
        __syncthreads();
        inc += add;
        ts[tid] = inc;
        __syncthreads();
    }
    if (tid < nb) bsums[tid] = inc - v;
}

__global__ __launch_bounds__(256) void k_scan3(int* __restrict__ row_off, const int* __restrict__ bsums) {
    int i = blockIdx.x * 256 + threadIdx.x;
    row_off[i] += bsums[i >> 10];
    if (i == 0) row_off[NN_TOT] = E_TOT;
}

// ---------------- CSR scatter: packed (src, norm) int2 ----------------
__global__ __launch_bounds__(256) void k_scatter(const int* __restrict__ src, const int* __restrict__ dst,
                                                 const float* __restrict__ d_isqrt, const int* __restrict__ row_off,
                                                 int* __restrict__ cursor, int2* __restrict__ er) {
    int e = blockIdx.x * 256 + threadIdx.x;
    int s = src[e], d = dst[e];
    float en = d_isqrt[s] * d_isqrt[d];
    int p = atomicAdd(&cursor[d], 1);
    int idx = row_off[d] + p;
    er[idx] = make_int2(s, __float_as_int(en));
}

// ---------------- GCN layer 0: 64 nodes/block, 4 edge-slots/node, then block matvec ----------------
__global__ __launch_bounds__(256) void k_gcn0(const float* __restrict__ x, const int* __restrict__ row_off,
                                              const int2* __restrict__ er, const float* __restrict__ self_norm,
                                              const float* __restrict__ W0, const float* __restrict__ b0,
                                              _Float16* __restrict__ h0) {
    __shared__ float zs[64][4];
    const int tid = threadIdx.x;
    const int blk = blockIdx.x;
    {
        const int li = tid >> 2;         // local node 0..63
        const int slot = tid & 3;        // edge slot
        const int n = blk * 64 + li;
        const int beg = row_off[n], end = row_off[n + 1];
        float p0 = 0.f, p1 = 0.f, p2 = 0.f;
        for (int ei = beg + slot; ei < end; ei += 4) {
            int2 e = er[ei];
            float en = __int_as_float(e.y);
            const float* xs = x + 3 * (size_t)e.x;
            p0 = fmaf(xs[0], en, p0);
            p1 = fmaf(xs[1], en, p1);
            p2 = fmaf(xs[2], en, p2);
        }
        p0 += __shfl_xor(p0, 1); p1 += __shfl_xor(p1, 1); p2 += __shfl_xor(p2, 1);
        p0 += __shfl_xor(p0, 2); p1 += __shfl_xor(p1, 2); p2 += __shfl_xor(p2, 2);
        if (slot == 0) {
            const float sn = self_norm[n];
            const float* xn = x + 3 * (size_t)n;
            zs[li][0] = fmaf(xn[0], sn, p0);
            zs[li][1] = fmaf(xn[1], sn, p1);
            zs[li][2] = fmaf(xn[2], sn, p2);
        }
    }
    __syncthreads();
    // matvec: thread = col-pair jj, 16 nodes per wave-group
    const int jj = tid & 63;                  // col pair 0..63
    const int g = tid >> 6;                   // node group 0..3
    const int j = jj * 2;
    const float w00 = W0[j], w01 = W0[j + 1];
    const float w10 = W0[128 + j], w11 = W0[128 + j + 1];
    const float w20 = W0[256 + j], w21 = W0[256 + j + 1];
    const float bb0 = b0[j], bb1 = b0[j + 1];
#pragma unroll 4
    for (int i = 0; i < 16; ++i) {
        const int li = g * 16 + i;
        const float z0 = zs[li][0], z1 = zs[li][1], z2 = zs[li][2];
        float o0 = bb0 + z0 * w00 + z1 * w10 + z2 * w20;
        float o1 = bb1 + z0 * w01 + z1 * w11 + z2 * w21;
        f16x2v o;
        o[0] = (_Float16)fmaxf(o0, 0.f);
        o[1] = (_Float16)fmaxf(o1, 0.f);
        *(f16x2v*)(h0 + (size_t)(blk * 64 + li) * HID + j) = o;
    }
}

// ---------------- fused: aggregation (lane-per-node, wave-per-feature-slice) + GEMM1 MFMA -> h1 ----
__global__ __launch_bounds__(256) void k_agg_mm(const _Float16* __restrict__ h0, const int* __restrict__ row_off,
                                                const int2* __restrict__ er, const float* __restrict__ self_norm,
                                                const _Float16* __restrict__ W1p, const float* __restrict__ b1,
                                                _Float16* __restrict__ h1) {
    __shared__ __align__(16) _Float16 As[64 * 136];  // rows padded to 136 f16 (272 B)
    const int tid = threadIdx.x;
    const int w = tid >> 6, lane = tid & 63;
    const int blk = blockIdx.x;

    // phase 1: per-lane gather-accumulate over own node's edges (cols w*32 + 0..31)
    {
        const int node = blk * 64 + lane;
        const int beg = row_off[node], end = row_off[node + 1];
        const _Float16* __restrict__ hcol = h0 + w * 32;
        f32x4 acc[8];
#pragma unroll
        for (int k = 0; k < 8; ++k) acc[k] = (f32x4){0.f, 0.f, 0.f, 0.f};
        {
            const float sn = self_norm[node];
            const f16x8* rp = (const f16x8*)(hcol + (size_t)node * HID);
#pragma unroll
            for (int v4 = 0; v4 < 4; ++v4) {
                f16x8 v = rp[v4];
#pragma unroll
                for (int k = 0; k < 8; ++k) acc[v4 * 2 + (k >> 2)][k & 3] = fmaf((float)v[k], sn, acc[v4 * 2 + (k >> 2)][k & 3]);
            }
        }
        for (int ei = beg; ei < end; ++ei) {
            int2 e = er[ei];
            float en = __int_as_float(e.y);
            const f16x8* rp = (const f16x8*)(hcol + (size_t)e.x * HID);
            f16x8 v0 = rp[0], v1 = rp[1], v2 = rp[2], v3 = rp[3];
#pragma unroll
            for (int k = 0; k < 8; ++k) acc[0 + (k >> 2)][k & 3] = fmaf((float)v0[k], en, acc[0 + (k >> 2)][k & 3]);
#pragma unroll
            for (int k = 0; k < 8; ++k) acc[2 + (k >> 2)][k & 3] = fmaf((float)v1[k], en, acc[2 + (k >> 2)][k & 3]);
#pragma unroll
            for (int k = 0; k < 8; ++k) acc[4 + (k >> 2)][k & 3] = fmaf((float)v2[k], en, acc[4 + (k >> 2)][k & 3]);
#pragma unroll
            for (int k = 0; k < 8; ++k) acc[6 + (k >> 2)][k & 3] = fmaf((float)v3[k], en, acc[6 + (k >> 2)][k & 3]);
        }
        _Float16* dst = &As[lane * 136 + w * 32];
#pragma unroll
        for (int v4 = 0; v4 < 4; ++v4) {
            f16x8 o;
#pragma unroll
            for (int k = 0; k < 8; ++k) o[k] = (_Float16)acc[v4 * 2 + (k >> 2)][k & 3];
            *(f16x8*)(dst + v4 * 8) = o;
        }
    }
    __syncthreads();

    // phase 2: MFMA 16x128x128; wave w owns m-tile rows w*16..w*16+15
    const int q = lane >> 4, c = lane & 15;
    f16x8 afr[4];
#pragma unroll
    for (int kk = 0; kk < 4; ++kk) afr[kk] = *(const f16x8*)(&As[(w * 16 + c) * 136 + kk * 32 + q * 8]);
    const f16x8* __restrict__ Bv = (const f16x8*)W1p;
    _Float16* Cst = &As[w * 2176];
#pragma unroll
    for (int j = 0; j < 8; ++j) {
        f32x4 cc = {0.f, 0.f, 0.f, 0.f};
#pragma unroll
        for (int kk = 0; kk < 4; ++kk)
            cc = __builtin_amdgcn_mfma_f32_16x16x32_f16(afr[kk], Bv[(j * 4 + kk) * 64 + lane], cc, 0, 0, 0);
        const float bi = b1[j * 16 + c];
#pragma unroll
        for (int r = 0; r < 4; ++r) Cst[(q * 4 + r) * 128 + j * 16 + c] = (_Float16)fmaxf(cc[r] + bi, 0.f);
    }
#pragma unroll
    for (int it = 0; it < 4; ++it) {
        int idx = it * 64 + lane;
        *(f16x8*)(h1 + (size_t)(blk * 64 + w * 16) * 128 + idx * 8) = *(const f16x8*)(&As[w * 2176 + idx * 8]);
    }
}

// ---------------- weight prep: WihT (f32) + MFMA fragment packs (f16) ----------------
__global__ __launch_bounds__(256) void k_prep(const float* __restrict__ Wih, const float* __restrict__ W1,
                                              const float* __restrict__ Wm, float* __restrict__ WihT,
                                              _Float16* __restrict__ W1p, _Float16* __restrict__ Wmp) {
    int i = blockIdx.x * 256 + threadIdx.x;  // 0..49151
    {
        int o = i >> 7, k = i & 127;
        WihT[k * 384 + o] = Wih[i];
    }
    if (i < 16384) {
        int f = i >> 9;          // frag id 0..31
        int j = f >> 2, kk = f & 3;
        int lane = (i >> 3) & 63;
        int e = i & 7;
        int q = lane >> 4, p = lane & 15;
        int k = kk * 32 + q * 8 + e, n = j * 16 + p;
        W1p[i] = (_Float16)W1[k * 128 + n];
        Wmp[i] = (_Float16)Wm[k * 128 + n];
    }
}

// ---------------- fused: GEMM2 (f16 MFMA) + relu + frame mean + gi precompute (time-major out) ----
__global__ __launch_bounds__(256) void k_mm_pool(const _Float16* __restrict__ h1, const _Float16* __restrict__ Wmp,
                                                 const float* __restrict__ bm, const float* __restrict__ WihT,
                                                 const float* __restrict__ bih, float* __restrict__ GIt) {
    __shared__ __align__(16) _Float16 As[80 * 136];
    __shared__ float colpart[4 * 128];
    __shared__ float fr[128];
    const int tid = threadIdx.x;
    const int w = tid >> 6, lane = tid & 63;
    const int q = lane >> 4, c = lane & 15;
    const int bt = blockIdx.x;
    const int bb = bt / T_SZ, tt = bt % T_SZ;

    const f16x8* __restrict__ srcv = (const f16x8*)(h1 + (size_t)bt * NPF * HID);
    for (int idx = tid; idx < 80 * 17; idx += 256) {
        int row = idx / 17, ch = idx % 17;
        f16x8 v;
        if (row < NPF && ch < 16) {
            v = srcv[row * 16 + ch];
        } else {
#pragma unroll
            for (int k = 0; k < 8; ++k) v[k] = (_Float16)0.f;
        }
        *(f16x8*)(&As[row * 136 + ch * 8]) = v;
    }
    __syncthreads();

    const f16x8* __restrict__ Bv = (const f16x8*)Wmp;
    const int npass = (w == 0) ? 2 : 1;
    for (int pass = 0; pass < npass; ++pass) {
        const int mt = pass ? 4 : w;
        f16x8 afr[4];
#pragma unroll
        for (int kk = 0; kk < 4; ++kk) afr[kk] = *(const f16x8*)(&As[(mt * 16 + c) * 136 + kk * 32 + q * 8]);
#pragma unroll
        for (int j = 0; j < 8; ++j) {
            f32x4 cc = {0.f, 0.f, 0.f, 0.f};
#pragma unroll
            for (int kk = 0; kk < 4; ++kk)
                cc = __builtin_amdgcn_mfma_f32_16x16x32_f16(afr[kk], Bv[(j * 4 + kk) * 64 + lane], cc, 0, 0, 0);
            const float bi = bm[j * 16 + c];
            float s = 0.f;
#pragma unroll
            for (int r = 0; r < 4; ++r) {
                int m = mt * 16 + q * 4 + r;
                float v = fmaxf(cc[r] + bi, 0.f);
                s += (m < NPF) ? v : 0.f;
            }
            s += __shfl_xor(s, 16);
            s += __shfl_xor(s, 32);
            if (lane < 16) {
                float* dst = &colpart[w * 128 + j * 16 + c];
                *dst = (pass == 0) ? s : (*dst + s);
            }
        }
    }
    __syncthreads();
    if (tid < 128)
        fr[tid] = (colpart[tid] + colpart[128 + tid] + colpart[256 + tid] + colpart[384 + tid]) * (1.0f / NPF);
    __syncthreads();
    if (tid < 128) {
#pragma unroll
        for (int p = 0; p < 3; ++p) {
            int o = tid + p * 128;
            float a = bih[o];
#pragma unroll 8
            for (int k = 0; k < 128; ++k) a = fmaf(fr[k], WihT[k * 384 + o], a);
            GIt[((size_t)tt * B_SZ + bb) * 384 + o] = a;  // time-major for the GRU
        }
    }
}

// ---------------- GRU recurrence: MFMA-batched (16 batches = M-tile), 2 blocks x 8 waves ----------
// Wave w owns n-tiles {w, 8+w, 16+w} = gates r/z/n of outputs 16w..16w+15 -> gate math is lane-local.
// launch_bounds(512,2): 256-VGPR cap so the 48-reg weight fragments stay resident (64-VGPR cap spilled them).
__global__ __launch_bounds__(512, 2) void k_gru(const float* __restrict__ GIt, const float* __restrict__ Whh,
                                                const float* __restrict__ bhh, float* __restrict__ hT) {
    __shared__ __align__(16) _Float16 hbuf[2][16 * 144];  // double buffer: one barrier/step
    const int tid = threadIdx.x;
    const int w = tid >> 6, lane = tid & 63;
    const int q = lane >> 4, c = lane & 15;
    const int B = blockIdx.x;  // batches 16B..16B+15

    // B-frags from global Whh (row o = output, col k = feature), cvt to f16: 48 VGPRs
    f16x8 bfr[3][4];
#pragma unroll
    for (int g = 0; g < 3; ++g) {
        const int o = g * 128 + 16 * w + c;
#pragma unroll
        for (int kk = 0; kk < 4; ++kk) {
            const float* p = Whh + (size_t)o * 128 + kk * 32 + q * 8;
            float4 u = *(const float4*)p, v = *(const float4*)(p + 4);
            f16x8 f;
            f[0] = (_Float16)u.x; f[1] = (_Float16)u.y; f[2] = (_Float16)u.z; f[3] = (_Float16)u.w;
            f[4] = (_Float16)v.x; f[5] = (_Float16)v.y; f[6] = (_Float16)v.z; f[7] = (_Float16)v.w;
            bfr[g][kk] = f;
        }
    }
    const float bh0 = bhh[16 * w + c], bh1 = bhh[128 + 16 * w + c], bh2 = bhh[256 + 16 * w + c];
    for (int i = tid; i < 16 * 144 / 2; i += 512) ((unsigned int*)hbuf[0])[i] = 0u;
    float h[4] = {0.f, 0.f, 0.f, 0.f};
    float gc[3][4];
#pragma unroll
    for (int r = 0; r < 4; ++r) {
        size_t row = (size_t)(B * 16 + q * 4 + r) * 384 + 16 * w + c;  // t = 0
#pragma unroll
        for (int g = 0; g < 3; ++g) gc[g][r] = GIt[row + g * 128];
    }
    __syncthreads();

    for (int t = 0; t < T_SZ; ++t) {
        const _Float16* rb = hbuf[t & 1];
        _Float16* wb = hbuf[(t & 1) ^ 1];
        f16x8 afr[4];
#pragma unroll
        for (int kk = 0; kk < 4; ++kk) afr[kk] = *(const f16x8*)(&rb[c * 144 + kk * 32 + q * 8]);
        // prefetch next step's gi (L2-resident, hidden behind MFMA)
        float gn[3][4];
        const int tn = (t + 1 < T_SZ) ? t + 1 : T_SZ - 1;
#pragma unroll
        for (int r = 0; r < 4; ++r) {
            size_t row = ((size_t)tn * B_SZ + B * 16 + q * 4 + r) * 384 + 16 * w + c;
#pragma unroll
            for (int g = 0; g < 3; ++g) gn[g][r] = GIt[row + g * 128];
        }
        f32x4 cc[3];
#pragma unroll
        for (int g = 0; g < 3; ++g) {
            f32x4 a = {0.f, 0.f, 0.f, 0.f};
#pragma unroll
            for (int kk = 0; kk < 4; ++kk) a = __builtin_amdgcn_mfma_f32_16x16x32_f16(afr[kk], bfr[g][kk], a, 0, 0, 0);
            cc[g] = a;
        }
#pragma unroll
        for (int r = 0; r < 4; ++r) {
            float hr = cc[0][r] + bh0, hz = cc[1][r] + bh1, hn = cc[2][r] + bh2;
            float rg = 1.f / (1.f + __expf(-(gc[0][r] + hr)));
            float zg = 1.f / (1.f + __expf(-(gc[1][r] + hz)));
            float arg = gc[2][r] + rg * hn;
            float nn = 1.f - 2.f / (__expf(2.f * arg) + 1.f);
            h[r] = (1.f - zg) * nn + zg * h[r];
            wb[(q * 4 + r) * 144 + 16 * w + c] = (_Float16)h[r];
        }
#pragma unroll
        for (int r = 0; r < 4; ++r) {
            gc[0][r] = gn[0][r]; gc[1][r] = gn[1][r]; gc[2][r] = gn[2][r];
        }
        __syncthreads();  // new h visible for next step's frag reads
    }
#pragma unroll
    for (int r = 0; r < 4; ++r) hT[(size_t)(B * 16 + q * 4 + r) * 128 + 16 * w + c] = h[r];
}

// ---------------- classifier head (384 threads: phase 2 needs 320) ----------------
__global__ __launch_bounds__(384) void k_cls(const float* __restrict__ hT, const float* __restrict__ Wc1,
                                             const float* __restrict__ bc1, const float* __restrict__ Wc2,
                                             const float* __restrict__ bc2, float* __restrict__ out) {
    __shared__ float hid[32 * 64];
    int tid = threadIdx.x;
    for (int idx = tid; idx < 2048; idx += 384) {
        int b = idx >> 6, j = idx & 63;
        float a = bc1[j];
#pragma unroll 8
        for (int k = 0; k < 128; ++k) a = fmaf(hT[b * 128 + k], Wc1[k * 64 + j], a);
        hid[idx] = fmaxf(a, 0.f);
    }
    __syncthreads();
    if (tid < 320) {
        int b = tid / 10, c = tid % 10;
        float a = bc2[c];
#pragma unroll 8
        for (int k = 0; k < 64; ++k) a = fmaf(hid[b * 64 + k], Wc2[k * 10 + c], a);
        out[tid] = a;
    }
}

extern "C" void kernel_launch(void* const* d_in, const int* in_sizes, int n_in, void* d_out, int out_size, void* d_ws,
                              size_t ws_size, hipStream_t stream) {
    const float* x = (const float*)d_in[0];
    const int* ei = (const int*)d_in[1];
    const int* e_src = ei;
    const int* e_dst = ei + E_TOT;
    const float* W0 = (const float*)d_in[2];
    const float* b0 = (const float*)d_in[3];
    const float* W1 = (const float*)d_in[4];
    const float* b1 = (const float*)d_in[5];
    const float* Wm = (const float*)d_in[6];
    const float* bm = (const float*)d_in[7];
    const float* Wih = (const float*)d_in[8];
    const float* Whh = (const float*)d_in[9];
    const float* bih = (const float*)d_in[10];
    const float* bhh = (const float*)d_in[11];
    const float* Wc1 = (const float*)d_in[12];
    const float* bc1 = (const float*)d_in[13];
    const float* Wc2 = (const float*)d_in[14];
    const float* bc2 = (const float*)d_in[15];
    float* out = (float*)d_out;

    char* base = (char*)d_ws;
    size_t off = 0;
    auto alloc = [&](size_t bytes) {
        size_t o = off;
        off = (off + bytes + 255) & ~(size_t)255;
        return o;
    };
    size_t o_cnt = alloc((size_t)NN_TOT * 4);
    size_t o_cursor = alloc((size_t)NN_TOT * 4);  // contiguous with cnt for one memset
    size_t o_rowoff = alloc((size_t)(NN_TOT + 1) * 4);
    size_t o_bsums = alloc(256 * 4);
    size_t o_disqrt = alloc((size_t)NN_TOT * 4);
    size_t o_snorm = alloc((size_t)NN_TOT * 4);
    size_t o_er = alloc((size_t)E_TOT * 8);
    size_t o_gi = alloc((size_t)B_SZ * T_SZ * 384 * 4);
    size_t o_wiht = alloc((size_t)128 * 384 * 4);
    size_t o_w1p = alloc((size_t)128 * 128 * 2);
    size_t o_wmp = alloc((size_t)128 * 128 * 2);
    size_t o_ht = alloc((size_t)B_SZ * 128 * 4);
    size_t o_h0 = alloc((size_t)NN_TOT * HID * 2);
    size_t o_h1 = alloc((size_t)NN_TOT * HID * 2);
    if (off > ws_size) return;  // workspace too small -> visible validation failure

    int* cnt = (int*)(base + o_cnt);
    int* cursor = (int*)(base + o_cursor);
    int* row_off = (int*)(base + o_rowoff);
    int* bsums = (int*)(base + o_bsums);
    float* d_isqrt = (float*)(base + o_disqrt);
    float* self_norm = (float*)(base + o_snorm);
    int2* er = (int2*)(base + o_er);
    float* GIt = (float*)(base + o_gi);
    float* WihT = (float*)(base + o_wiht);
    _Float16* W1p = (_Float16*)(base + o_w1p);
    _Float16* Wmp = (_Float16*)(base + o_wmp);
    float* hT = (float*)(base + o_ht);
    _Float16* h0 = (_Float16*)(base + o_h0);
    _Float16* h1 = (_Float16*)(base + o_h1);

    hipMemsetAsync(base + o_cnt, 0, (size_t)2 * NN_TOT * 4, stream);  // cnt + cursor

    k_deg<<<E_TOT / 1024, 256, 0, stream>>>((const int4*)e_dst, cnt);
    k_scan1<<<NN_TOT / 1024, 256, 0, stream>>>(cnt, row_off, bsums, d_isqrt, self_norm);
    k_scan2<<<1, 256, 0, stream>>>(bsums, NN_TOT / 1024);
    k_scan3<<<NN_TOT / 256, 256, 0, stream>>>(row_off, bsums);
    k_scatter<<<E_TOT / 256, 256, 0, stream>>>(e_src, e_dst, d_isqrt, row_off, cursor, er);
    k_prep<<<(384 * 128) / 256, 256, 0, stream>>>(Wih, W1, Wm, WihT, W1p, Wmp);
    k_gcn0<<<NN_TOT / 64, 256, 0, stream>>>(x, row_off, er, self_norm, W0, b0, h0);
    k_agg_mm<<<NN_TOT / 64, 256, 0, stream>>>(h0, row_off, er, self_norm, W1p, b1, h1);
    k_mm_pool<<<B_SZ * T_SZ, 256, 0, stream>>>(h1, Wmp, bm, WihT, bih, GIt);
    k_gru<<<2, 512, 0, stream>>>(GIt, Whh, bhh, hT);
    k_cls<<<1, 384, 0, stream>>>(hT, Wc1, bc1, Wc2, bc2, out);
}